// Round 1
// baseline (773.962 us; speedup 1.0000x reference)
//
#include <hip/hip_runtime.h>

#define HH 96
#define WW 96
#define CC 3
#define OH 90
#define OW 90
#define NPATCH 8100
#define DD 147
#define DPAD 148
#define NPROJ 256
#define TN 32
#define SORT_N 8192

// ---------------------------------------------------------------------------
// Kernel A: extract patches (Unfold layout f = c*49 + di*7 + dj), materialize
// xp/yp [N, 147], and compute projections pxT/pyT [256, N] (transposed for the
// sort kernel's coalesced column reads). std-normalization of rand is skipped:
// it is a positive per-column scale and cannot change the per-column argsort.
// ---------------------------------------------------------------------------
__global__ __launch_bounds__(256)
void patch_proj_kernel(const float* __restrict__ x, const float* __restrict__ y,
                       const float* __restrict__ rnd,
                       float* __restrict__ xp, float* __restrict__ yp,
                       float* __restrict__ pxT, float* __restrict__ pyT,
                       float* __restrict__ out)
{
    __shared__ float sx[TN * DPAD];
    __shared__ float sy[TN * DPAD];
    const int tid = threadIdx.x;
    const int n0 = blockIdx.x * TN;
    if (blockIdx.x == 0 && tid == 0) out[0] = 0.0f;  // reduce kernel runs later in stream

    for (int idx = tid; idx < TN * DD; idx += 256) {
        const int t = idx / DD;
        const int d = idx - t * DD;
        const int n = n0 + t;
        float vx = 0.f, vy = 0.f;
        if (n < NPATCH) {
            const int oy = n / OW, ox = n - oy * OW;
            const int c  = d / 49, r  = d - c * 49;
            const int di = r / 7,  dj = r - di * 7;
            const int off = c * (HH * WW) + (oy + di) * WW + (ox + dj);
            vx = x[off];
            vy = y[off];
            xp[n * DD + d] = vx;
            yp[n * DD + d] = vy;
        }
        sx[t * DPAD + d] = vx;
        sy[t * DPAD + d] = vy;
    }
    for (int t = tid; t < TN; t += 256) {  // zero the pad column (d = 147)
        sx[t * DPAD + DD] = 0.f;
        sy[t * DPAD + DD] = 0.f;
    }
    __syncthreads();

    const int p = tid;  // one projection per thread
    float accx[TN], accy[TN];
#pragma unroll
    for (int t = 0; t < TN; ++t) { accx[t] = 0.f; accy[t] = 0.f; }

    for (int d = 0; d < 144; d += 4) {
        const float r0 = rnd[(d + 0) * NPROJ + p];
        const float r1 = rnd[(d + 1) * NPROJ + p];
        const float r2 = rnd[(d + 2) * NPROJ + p];
        const float r3 = rnd[(d + 3) * NPROJ + p];
#pragma unroll
        for (int t = 0; t < TN; ++t) {
            const float4 xv = *(const float4*)&sx[t * DPAD + d];
            const float4 yv = *(const float4*)&sy[t * DPAD + d];
            accx[t] += xv.x * r0 + xv.y * r1 + xv.z * r2 + xv.w * r3;
            accy[t] += yv.x * r0 + yv.y * r1 + yv.z * r2 + yv.w * r3;
        }
    }
    {   // tail d = 144..146 (pad element 147 is zero)
        const float r0 = rnd[144 * NPROJ + p];
        const float r1 = rnd[145 * NPROJ + p];
        const float r2 = rnd[146 * NPROJ + p];
#pragma unroll
        for (int t = 0; t < TN; ++t) {
            const float4 xv = *(const float4*)&sx[t * DPAD + 144];
            const float4 yv = *(const float4*)&sy[t * DPAD + 144];
            accx[t] += xv.x * r0 + xv.y * r1 + xv.z * r2;
            accy[t] += yv.x * r0 + yv.y * r1 + yv.z * r2;
        }
    }
#pragma unroll
    for (int t = 0; t < TN; ++t) {
        const int n = n0 + t;
        if (n < NPATCH) {
            pxT[(size_t)p * NPATCH + n] = accx[t];
            pyT[(size_t)p * NPATCH + n] = accy[t];
        }
    }
}

// ---------------------------------------------------------------------------
// Kernel B: per-column argsort via LDS bitonic sort of 8192 packed u64 keys
// (order-preserving f32 transform << 13 | index). blockIdx.x in [0,512):
// columns of pxT then pyT (adjacent in workspace); outputs ix then iy.
// ---------------------------------------------------------------------------
__global__ __launch_bounds__(256)
void sort_kernel(const float* __restrict__ pT, unsigned short* __restrict__ idxOut)
{
    __shared__ unsigned long long sk[SORT_N];  // 64 KB
    const int p = blockIdx.x;
    const int tid = threadIdx.x;
    const float* col = pT + (size_t)p * NPATCH;

    for (int i = tid; i < SORT_N; i += 256) {
        unsigned long long v;
        if (i < NPATCH) {
            const unsigned u = __float_as_uint(col[i]);
            const unsigned s = (u & 0x80000000u) ? ~u : (u | 0x80000000u);
            v = ((unsigned long long)s << 13) | (unsigned)i;
        } else {
            v = ~0ull;  // +inf pad, sorts to the tail
        }
        sk[i] = v;
    }

    for (int k2 = 2; k2 <= SORT_N; k2 <<= 1) {
        for (int j = k2 >> 1; j > 0; j >>= 1) {
            __syncthreads();
            for (int i = tid; i < SORT_N; i += 256) {
                const int l = i ^ j;
                if (l > i) {
                    const unsigned long long a = sk[i];
                    const unsigned long long b = sk[l];
                    const bool up = ((i & k2) == 0);
                    if ((a > b) == up) { sk[i] = b; sk[l] = a; }
                }
            }
        }
    }
    __syncthreads();

    for (int k = tid; k < NPATCH; k += 256)
        idxOut[(size_t)p * NPATCH + k] = (unsigned short)(sk[k] & 0x1FFFu);
}

// ---------------------------------------------------------------------------
// Kernel C: loss = mean over (p, k, d) of |xp[ix[p,k], d] - yp[iy[p,k], d]|.
// One wave per k (lanes over d: coalesced 64/64/19-lane row reads).
// ---------------------------------------------------------------------------
__global__ __launch_bounds__(256)
void reduce_kernel(const float* __restrict__ xp, const float* __restrict__ yp,
                   const unsigned short* __restrict__ ix,
                   const unsigned short* __restrict__ iy,
                   float* __restrict__ out)
{
    const int p = blockIdx.x;
    const int nb = gridDim.y;
    const int kpb = (NPATCH + nb - 1) / nb;
    const int k0 = blockIdx.y * kpb;
    const int kend = min(k0 + kpb, NPATCH);
    const int tid = threadIdx.x;
    const int wave = tid >> 6, lane = tid & 63;

    const unsigned short* ixp = ix + (size_t)p * NPATCH;
    const unsigned short* iyp = iy + (size_t)p * NPATCH;

    float acc = 0.f;
    for (int k = k0 + wave; k < kend; k += 4) {
        const int i = ixp[k];
        const int j = iyp[k];
        const float* xr = xp + i * DD;
        const float* yr = yp + j * DD;
        acc += fabsf(xr[lane]      - yr[lane]);
        acc += fabsf(xr[lane + 64] - yr[lane + 64]);
        if (lane < DD - 128)
            acc += fabsf(xr[lane + 128] - yr[lane + 128]);
    }

#pragma unroll
    for (int o = 32; o > 0; o >>= 1) acc += __shfl_down(acc, o, 64);

    __shared__ float sred[4];
    if (lane == 0) sred[wave] = acc;
    __syncthreads();
    if (tid == 0) {
        const float s = sred[0] + sred[1] + sred[2] + sred[3];
        atomicAdd(out, s * (1.0f / ((float)NPROJ * (float)NPATCH * (float)DD)));
    }
}

// ---------------------------------------------------------------------------
extern "C" void kernel_launch(void* const* d_in, const int* in_sizes, int n_in,
                              void* d_out, int out_size, void* d_ws, size_t ws_size,
                              hipStream_t stream)
{
    const float* x   = (const float*)d_in[0];
    const float* y   = (const float*)d_in[1];
    const float* rnd = (const float*)d_in[2];

    char* ws = (char*)d_ws;
    // workspace layout (16B-aligned, pxT|pyT and ix|iy deliberately adjacent):
    float*          xp  = (float*)(ws + 0);          // 8100*147*4 = 4,762,800
    float*          yp  = (float*)(ws + 4762800);    // 4,762,800
    float*          pxT = (float*)(ws + 9525600);    // 256*8100*4 = 8,294,400
    float*          pyT = (float*)(ws + 17820000);   // 8,294,400
    unsigned short* ix  = (unsigned short*)(ws + 26114400);  // 256*8100*2 = 4,147,200
    unsigned short* iy  = (unsigned short*)(ws + 30261600);  // 4,147,200
    // total: 34,408,800 bytes
    float* out = (float*)d_out;

    hipLaunchKernelGGL(patch_proj_kernel, dim3((NPATCH + TN - 1) / TN), dim3(256), 0, stream,
                       x, y, rnd, xp, yp, pxT, pyT, out);
    hipLaunchKernelGGL(sort_kernel, dim3(2 * NPROJ), dim3(256), 0, stream, pxT, ix);
    hipLaunchKernelGGL(reduce_kernel, dim3(NPROJ, 16), dim3(256), 0, stream,
                       xp, yp, ix, iy, out);
}

// Round 2
// 528.827 us; speedup vs baseline: 1.4635x; 1.4635x over previous
//
#include <hip/hip_runtime.h>
#include <hip/hip_fp16.h>

#define HH 96
#define WW 96
#define CC 3
#define OH 90
#define OW 90
#define NPATCH 8100
#define DD 147
#define DPAD 148
#define NPROJ 256
#define TN 32
#define SORT_N 8192

// ---------------------------------------------------------------------------
// Kernel A: extract patches (Unfold layout f = c*49 + di*7 + dj), materialize
// fp16 gather copies xp16/yp16 [N, 148] (pad col = 0), and compute projections
// pxT/pyT [256, N] (transposed for the sort kernel's coalesced column reads).
// std-normalization of rand is skipped: it is a positive per-column scale and
// cannot change the per-column argsort.
// ---------------------------------------------------------------------------
__global__ __launch_bounds__(256)
void patch_proj_kernel(const float* __restrict__ x, const float* __restrict__ y,
                       const float* __restrict__ rnd,
                       __half* __restrict__ xp16, __half* __restrict__ yp16,
                       float* __restrict__ pxT, float* __restrict__ pyT,
                       float* __restrict__ out)
{
    __shared__ float sx[TN * DPAD];
    __shared__ float sy[TN * DPAD];
    const int tid = threadIdx.x;
    const int n0 = blockIdx.x * TN;
    if (blockIdx.x == 0 && tid == 0) out[0] = 0.0f;  // reduce kernel runs later in stream

    for (int idx = tid; idx < TN * DD; idx += 256) {
        const int t = idx / DD;
        const int d = idx - t * DD;
        const int n = n0 + t;
        float vx = 0.f, vy = 0.f;
        if (n < NPATCH) {
            const int oy = n / OW, ox = n - oy * OW;
            const int c  = d / 49, r  = d - c * 49;
            const int di = r / 7,  dj = r - di * 7;
            const int off = c * (HH * WW) + (oy + di) * WW + (ox + dj);
            vx = x[off];
            vy = y[off];
            xp16[(size_t)n * DPAD + d] = __float2half(vx);
            yp16[(size_t)n * DPAD + d] = __float2half(vy);
        }
        sx[t * DPAD + d] = vx;
        sy[t * DPAD + d] = vy;
    }
    for (int t = tid; t < TN; t += 256) {  // zero the pad column (d = 147)
        sx[t * DPAD + DD] = 0.f;
        sy[t * DPAD + DD] = 0.f;
        const int n = n0 + t;
        if (n < NPATCH) {
            xp16[(size_t)n * DPAD + DD] = __float2half(0.f);
            yp16[(size_t)n * DPAD + DD] = __float2half(0.f);
        }
    }
    __syncthreads();

    const int p = tid;  // one projection per thread
    float accx[TN], accy[TN];
#pragma unroll
    for (int t = 0; t < TN; ++t) { accx[t] = 0.f; accy[t] = 0.f; }

    for (int d = 0; d < 144; d += 4) {
        const float r0 = rnd[(d + 0) * NPROJ + p];
        const float r1 = rnd[(d + 1) * NPROJ + p];
        const float r2 = rnd[(d + 2) * NPROJ + p];
        const float r3 = rnd[(d + 3) * NPROJ + p];
#pragma unroll
        for (int t = 0; t < TN; ++t) {
            const float4 xv = *(const float4*)&sx[t * DPAD + d];
            const float4 yv = *(const float4*)&sy[t * DPAD + d];
            accx[t] += xv.x * r0 + xv.y * r1 + xv.z * r2 + xv.w * r3;
            accy[t] += yv.x * r0 + yv.y * r1 + yv.z * r2 + yv.w * r3;
        }
    }
    {   // tail d = 144..146 (pad element 147 is zero)
        const float r0 = rnd[144 * NPROJ + p];
        const float r1 = rnd[145 * NPROJ + p];
        const float r2 = rnd[146 * NPROJ + p];
#pragma unroll
        for (int t = 0; t < TN; ++t) {
            const float4 xv = *(const float4*)&sx[t * DPAD + 144];
            const float4 yv = *(const float4*)&sy[t * DPAD + 144];
            accx[t] += xv.x * r0 + xv.y * r1 + xv.z * r2;
            accy[t] += yv.x * r0 + yv.y * r1 + yv.z * r2;
        }
    }
#pragma unroll
    for (int t = 0; t < TN; ++t) {
        const int n = n0 + t;
        if (n < NPATCH) {
            pxT[(size_t)p * NPATCH + n] = accx[t];
            pyT[(size_t)p * NPATCH + n] = accy[t];
        }
    }
}

// ---------------------------------------------------------------------------
// Kernel B: per-column argsort via LDS bitonic sort of 8192 packed u64 keys
// (order-preserving f32 transform << 13 | index — low-bit index = stable sort,
// matching jnp.argsort tie order). 512 threads iterate over the 4096 pair
// indices directly (no idle compare lanes). blockIdx.x in [0,512): columns of
// pxT then pyT (adjacent in workspace); outputs ix then iy (adjacent).
// ---------------------------------------------------------------------------
__global__ __launch_bounds__(512)
void sort_kernel(const float* __restrict__ pT, unsigned short* __restrict__ idxOut)
{
    __shared__ unsigned long long sk[SORT_N];  // 64 KB
    const int p = blockIdx.x;
    const int tid = threadIdx.x;
    const float* col = pT + (size_t)p * NPATCH;

    for (int i = tid; i < SORT_N; i += 512) {
        unsigned long long v;
        if (i < NPATCH) {
            const unsigned u = __float_as_uint(col[i]);
            const unsigned s = (u & 0x80000000u) ? ~u : (u | 0x80000000u);
            v = ((unsigned long long)s << 13) | (unsigned)i;
        } else {
            v = ~0ull;  // +inf pad, sorts to the tail
        }
        sk[i] = v;
    }

    for (int k2 = 2; k2 <= SORT_N; k2 <<= 1) {
        for (int j = k2 >> 1; j > 0; j >>= 1) {
            __syncthreads();
            const int jm = j - 1;
#pragma unroll 4
            for (int pid = tid; pid < SORT_N / 2; pid += 512) {
                const int i = ((pid & ~jm) << 1) | (pid & jm);
                const int l = i | j;
                const unsigned long long a = sk[i];
                const unsigned long long b = sk[l];
                const bool up = ((i & k2) == 0);
                if ((a > b) == up) { sk[i] = b; sk[l] = a; }
            }
        }
    }
    __syncthreads();

    for (int k = tid; k < NPATCH; k += 512)
        idxOut[(size_t)p * NPATCH + k] = (unsigned short)(sk[k] & 0x1FFFu);
}

// ---------------------------------------------------------------------------
// Kernel C: loss = mean over (p, k, d) of |xp[ix[p,k], d] - yp[iy[p,k], d]|.
// One wave per k; rows are fp16 padded to 148 -> two half2 loads per row
// (lanes 0..63 cover elems 0..127, lanes 0..9 cover 128..147, pad elem = 0).
// Diff accumulated in fp32.
// ---------------------------------------------------------------------------
__global__ __launch_bounds__(256)
void reduce_kernel(const __half* __restrict__ xp16, const __half* __restrict__ yp16,
                   const unsigned short* __restrict__ ix,
                   const unsigned short* __restrict__ iy,
                   float* __restrict__ out)
{
    const int p = blockIdx.x;
    const int nb = gridDim.y;
    const int kpb = (NPATCH + nb - 1) / nb;
    const int k0 = blockIdx.y * kpb;
    const int kend = min(k0 + kpb, NPATCH);
    const int tid = threadIdx.x;
    const int wave = tid >> 6, lane = tid & 63;

    const unsigned short* ixp = ix + (size_t)p * NPATCH;
    const unsigned short* iyp = iy + (size_t)p * NPATCH;

    float acc = 0.f;
    for (int k = k0 + wave; k < kend; k += 4) {
        const int i = ixp[k];
        const int j = iyp[k];
        const __half2* xr = (const __half2*)(xp16 + (size_t)i * DPAD);
        const __half2* yr = (const __half2*)(yp16 + (size_t)j * DPAD);
        const __half2 xa = xr[lane];
        const __half2 ya = yr[lane];
        const float2 xf = __half22float2(xa);
        const float2 yf = __half22float2(ya);
        acc += fabsf(xf.x - yf.x) + fabsf(xf.y - yf.y);
        if (lane < 10) {  // elements 128..147 (147 is the zero pad)
            const __half2 xb = xr[64 + lane];
            const __half2 yb = yr[64 + lane];
            const float2 xg = __half22float2(xb);
            const float2 yg = __half22float2(yb);
            acc += fabsf(xg.x - yg.x) + fabsf(xg.y - yg.y);
        }
    }

#pragma unroll
    for (int o = 32; o > 0; o >>= 1) acc += __shfl_down(acc, o, 64);

    __shared__ float sred[4];
    if (lane == 0) sred[wave] = acc;
    __syncthreads();
    if (tid == 0) {
        const float s = sred[0] + sred[1] + sred[2] + sred[3];
        atomicAdd(out, s * (1.0f / ((float)NPROJ * (float)NPATCH * (float)DD)));
    }
}

// ---------------------------------------------------------------------------
extern "C" void kernel_launch(void* const* d_in, const int* in_sizes, int n_in,
                              void* d_out, int out_size, void* d_ws, size_t ws_size,
                              hipStream_t stream)
{
    const float* x   = (const float*)d_in[0];
    const float* y   = (const float*)d_in[1];
    const float* rnd = (const float*)d_in[2];

    char* ws = (char*)d_ws;
    // workspace layout (16B-aligned; pxT|pyT and ix|iy deliberately adjacent):
    __half*         xp16 = (__half*)(ws + 0);          // 8100*148*2 = 2,397,600
    __half*         yp16 = (__half*)(ws + 2397600);    // 2,397,600
    float*          pxT  = (float*)(ws + 4795200);     // 256*8100*4 = 8,294,400
    float*          pyT  = (float*)(ws + 13089600);    // 8,294,400
    unsigned short* ix   = (unsigned short*)(ws + 21384000);  // 256*8100*2 = 4,147,200
    unsigned short* iy   = (unsigned short*)(ws + 25531200);  // 4,147,200
    // total: 29,678,400 bytes
    float* out = (float*)d_out;

    hipLaunchKernelGGL(patch_proj_kernel, dim3((NPATCH + TN - 1) / TN), dim3(256), 0, stream,
                       x, y, rnd, xp16, yp16, pxT, pyT, out);
    hipLaunchKernelGGL(sort_kernel, dim3(2 * NPROJ), dim3(512), 0, stream, pxT, ix);
    hipLaunchKernelGGL(reduce_kernel, dim3(NPROJ, 16), dim3(256), 0, stream,
                       xp16, yp16, ix, iy, out);
}

// Round 3
// 439.842 us; speedup vs baseline: 1.7596x; 1.2023x over previous
//
#include <hip/hip_runtime.h>
#include <hip/hip_fp16.h>

#define HH 96
#define WW 96
#define CC 3
#define OH 90
#define OW 90
#define NPATCH 8100
#define DD 147
#define DPAD 148
#define NPROJ 256
#define TN 32
#define SORT_N 8192
#define SORT_T 512
#define EPT 16

// ---------------------------------------------------------------------------
// Kernel A: extract patches (Unfold layout f = c*49 + di*7 + dj), materialize
// fp16 gather copies xp16/yp16 [N, 148] (pad col = 0), and compute projections
// pxT/pyT [256, N] (transposed, adjacent in ws so sort indexes them as one
// [512, N] array). std-normalization of rand is skipped: it is a positive
// per-column scale and cannot change the per-column argsort.
// ---------------------------------------------------------------------------
__global__ __launch_bounds__(256)
void patch_proj_kernel(const float* __restrict__ x, const float* __restrict__ y,
                       const float* __restrict__ rnd,
                       __half* __restrict__ xp16, __half* __restrict__ yp16,
                       float* __restrict__ pxT, float* __restrict__ pyT,
                       float* __restrict__ out)
{
    __shared__ float sx[TN * DPAD];
    __shared__ float sy[TN * DPAD];
    const int tid = threadIdx.x;
    const int n0 = blockIdx.x * TN;
    if (blockIdx.x == 0 && tid == 0) out[0] = 0.0f;  // reduce runs later in stream

    for (int idx = tid; idx < TN * DD; idx += 256) {
        const int t = idx / DD;
        const int d = idx - t * DD;
        const int n = n0 + t;
        float vx = 0.f, vy = 0.f;
        if (n < NPATCH) {
            const int oy = n / OW, ox = n - oy * OW;
            const int c  = d / 49, r  = d - c * 49;
            const int di = r / 7,  dj = r - di * 7;
            const int off = c * (HH * WW) + (oy + di) * WW + (ox + dj);
            vx = x[off];
            vy = y[off];
            xp16[(size_t)n * DPAD + d] = __float2half(vx);
            yp16[(size_t)n * DPAD + d] = __float2half(vy);
        }
        sx[t * DPAD + d] = vx;
        sy[t * DPAD + d] = vy;
    }
    for (int t = tid; t < TN; t += 256) {  // zero pad column (d = 147)
        sx[t * DPAD + DD] = 0.f;
        sy[t * DPAD + DD] = 0.f;
        const int n = n0 + t;
        if (n < NPATCH) {
            xp16[(size_t)n * DPAD + DD] = __float2half(0.f);
            yp16[(size_t)n * DPAD + DD] = __float2half(0.f);
        }
    }
    __syncthreads();

    const int p = tid;  // one projection per thread
    float accx[TN], accy[TN];
#pragma unroll
    for (int t = 0; t < TN; ++t) { accx[t] = 0.f; accy[t] = 0.f; }

    for (int d = 0; d < 144; d += 4) {
        const float r0 = rnd[(d + 0) * NPROJ + p];
        const float r1 = rnd[(d + 1) * NPROJ + p];
        const float r2 = rnd[(d + 2) * NPROJ + p];
        const float r3 = rnd[(d + 3) * NPROJ + p];
#pragma unroll
        for (int t = 0; t < TN; ++t) {
            const float4 xv = *(const float4*)&sx[t * DPAD + d];
            const float4 yv = *(const float4*)&sy[t * DPAD + d];
            accx[t] += xv.x * r0 + xv.y * r1 + xv.z * r2 + xv.w * r3;
            accy[t] += yv.x * r0 + yv.y * r1 + yv.z * r2 + yv.w * r3;
        }
    }
    {
        const float r0 = rnd[144 * NPROJ + p];
        const float r1 = rnd[145 * NPROJ + p];
        const float r2 = rnd[146 * NPROJ + p];
#pragma unroll
        for (int t = 0; t < TN; ++t) {
            const float4 xv = *(const float4*)&sx[t * DPAD + 144];
            const float4 yv = *(const float4*)&sy[t * DPAD + 144];
            accx[t] += xv.x * r0 + xv.y * r1 + xv.z * r2;
            accy[t] += yv.x * r0 + yv.y * r1 + yv.z * r2;
        }
    }
#pragma unroll
    for (int t = 0; t < TN; ++t) {
        const int n = n0 + t;
        if (n < NPATCH) {
            pxT[(size_t)p * NPATCH + n] = accx[t];
            pyT[(size_t)p * NPATCH + n] = accy[t];
        }
    }
}

// ---------------------------------------------------------------------------
// Kernel B: per-column argsort via hybrid register/LDS bitonic sort of 8192
// packed u64 keys (order-preserving f32 transform << 13 | index = stable).
// 512 threads x 16 elems/thread: all passes with j<16 run in registers (one
// LDS session per merge level); only j>=16 passes touch LDS. blockIdx.x in
// [0,512): cols of pxT (write RANK array rx[idx]=k, scattered) then pyT
// (write iy[k]=idx, sequential).
// ---------------------------------------------------------------------------
__global__ __launch_bounds__(SORT_T, 4)
void sort_kernel(const float* __restrict__ pT,
                 unsigned short* __restrict__ rxOut,
                 unsigned short* __restrict__ iyOut)
{
    __shared__ unsigned long long sk[SORT_N];  // 64 KB
    const int pb = blockIdx.x;
    const int tid = threadIdx.x;
    const float* col = pT + (size_t)pb * NPATCH;

    for (int i = tid; i < SORT_N; i += SORT_T) {
        unsigned long long v;
        if (i < NPATCH) {
            const unsigned u = __float_as_uint(col[i]);
            const unsigned s = (u & 0x80000000u) ? ~u : (u | 0x80000000u);
            v = ((unsigned long long)s << 13) | (unsigned)i;
        } else {
            v = ~0ull;  // +inf pad, strictly greater than any finite key
        }
        sk[i] = v;
    }
    __syncthreads();

    const int base = tid * EPT;
    unsigned long long r[EPT];

    // session 1: levels k2 = 2..16 entirely in-register
#pragma unroll
    for (int q = 0; q < EPT; ++q) r[q] = sk[base + q];
#pragma unroll
    for (int k2 = 2; k2 <= EPT; k2 <<= 1) {
#pragma unroll
        for (int j = k2 >> 1; j > 0; j >>= 1) {
#pragma unroll
            for (int q = 0; q < EPT; ++q) {
                const int l = q ^ j;
                if (l > q) {
                    const bool up = (((base + q) & k2) == 0);
                    const unsigned long long a = r[q], b = r[l];
                    if ((a > b) == up) { r[q] = b; r[l] = a; }
                }
            }
        }
    }
#pragma unroll
    for (int q = 0; q < EPT; ++q) sk[base + q] = r[q];

    // levels k2 = 32 .. 8192: j>=16 via LDS pair passes, j<16 in registers
    for (int k2 = 32; k2 <= SORT_N; k2 <<= 1) {
        for (int j = k2 >> 1; j >= EPT; j >>= 1) {
            __syncthreads();
            const int jm = j - 1;
#pragma unroll
            for (int t = 0; t < SORT_N / 2 / SORT_T; ++t) {
                const int pid = tid + t * SORT_T;
                const int i = ((pid & ~jm) << 1) | (pid & jm);
                const int l = i | j;
                const unsigned long long a = sk[i];
                const unsigned long long b = sk[l];
                const bool up = ((i & k2) == 0);
                if ((a > b) == up) { sk[i] = b; sk[l] = a; }
            }
        }
        __syncthreads();
        const bool up = ((base & k2) == 0);  // uniform across chunk (k2 >= 32)
#pragma unroll
        for (int q = 0; q < EPT; ++q) r[q] = sk[base + q];
#pragma unroll
        for (int j = EPT / 2; j > 0; j >>= 1) {
#pragma unroll
            for (int q = 0; q < EPT; ++q) {
                const int l = q ^ j;
                if (l > q) {
                    const unsigned long long a = r[q], b = r[l];
                    if ((a > b) == up) { r[q] = b; r[l] = a; }
                }
            }
        }
        if (k2 < SORT_N) {
#pragma unroll
            for (int q = 0; q < EPT; ++q) sk[base + q] = r[q];
        }
    }

    // outputs straight from registers (pads sort to tail: real ranks 0..8099)
    if (pb < NPROJ) {
        unsigned short* rk = rxOut + (size_t)pb * NPATCH;
#pragma unroll
        for (int q = 0; q < EPT; ++q) {
            const int idx = (int)(r[q] & 0x1FFFu);
            if (idx < NPATCH) rk[idx] = (unsigned short)(base + q);
        }
    } else {
        unsigned short* io = iyOut + (size_t)(pb - NPROJ) * NPATCH;
#pragma unroll
        for (int q = 0; q < EPT; ++q) {
            if (base + q < NPATCH) io[base + q] = (unsigned short)(r[q] & 0x1FFFu);
        }
    }
}

// ---------------------------------------------------------------------------
// Kernel B2: partner[p][i] = iy[p][ rx[p][i] ] — single index per reduce iter.
// iy slice is 16 KB -> L1-resident gather; rx read and partner write coalesced.
// ---------------------------------------------------------------------------
__global__ __launch_bounds__(256)
void partner_kernel(const unsigned short* __restrict__ rx,
                    const unsigned short* __restrict__ iy,
                    unsigned short* __restrict__ partner)
{
    const int p = blockIdx.x;
    const int ipb = (NPATCH + gridDim.y - 1) / gridDim.y;
    const int i0 = blockIdx.y * ipb;
    const int iend = min(i0 + ipb, NPATCH);
    const unsigned short* rxp = rx + (size_t)p * NPATCH;
    const unsigned short* iyp = iy + (size_t)p * NPATCH;
    unsigned short* pp = partner + (size_t)p * NPATCH;
    for (int i = i0 + threadIdx.x; i < iend; i += 256)
        pp[i] = iyp[rxp[i]];
}

// ---------------------------------------------------------------------------
// Kernel C: loss = mean over (p, i, d) of |xp[i, d] - yp[partner[p][i], d]|
// (summation reordered by x-rank: x stream is sequential, only y is a random
// gather with a 2.4 MB working set -> fits a single XCD L2). One wave per i.
// ---------------------------------------------------------------------------
__global__ __launch_bounds__(256)
void reduce_kernel(const __half* __restrict__ xp16, const __half* __restrict__ yp16,
                   const unsigned short* __restrict__ partner,
                   float* __restrict__ out)
{
    const int p = blockIdx.x;
    const int ipb = (NPATCH + gridDim.y - 1) / gridDim.y;
    const int i0 = blockIdx.y * ipb;
    const int iend = min(i0 + ipb, NPATCH);
    const int tid = threadIdx.x;
    const int wave = tid >> 6, lane = tid & 63;
    const unsigned short* par = partner + (size_t)p * NPATCH;

    float acc = 0.f;
#pragma unroll 2
    for (int i = i0 + wave; i < iend; i += 4) {
        const int j = par[i];
        const __half2* xr = (const __half2*)(xp16 + (size_t)i * DPAD);
        const __half2* yr = (const __half2*)(yp16 + (size_t)j * DPAD);
        const __half2 xa = xr[lane], ya = yr[lane];
        const float2 xf = __half22float2(xa), yf = __half22float2(ya);
        acc += fabsf(xf.x - yf.x) + fabsf(xf.y - yf.y);
        if (lane < 10) {  // elements 128..147 (147 is the zero pad)
            const __half2 xb = xr[64 + lane], yb = yr[64 + lane];
            const float2 xg = __half22float2(xb), yg = __half22float2(yb);
            acc += fabsf(xg.x - yg.x) + fabsf(xg.y - yg.y);
        }
    }

#pragma unroll
    for (int o = 32; o > 0; o >>= 1) acc += __shfl_down(acc, o, 64);

    __shared__ float sred[4];
    if (lane == 0) sred[wave] = acc;
    __syncthreads();
    if (tid == 0) {
        const float s = sred[0] + sred[1] + sred[2] + sred[3];
        atomicAdd(out, s * (1.0f / ((float)NPROJ * (float)NPATCH * (float)DD)));
    }
}

// ---------------------------------------------------------------------------
extern "C" void kernel_launch(void* const* d_in, const int* in_sizes, int n_in,
                              void* d_out, int out_size, void* d_ws, size_t ws_size,
                              hipStream_t stream)
{
    const float* x   = (const float*)d_in[0];
    const float* y   = (const float*)d_in[1];
    const float* rnd = (const float*)d_in[2];

    char* ws = (char*)d_ws;
    // workspace layout (16B-aligned; pxT|pyT must be adjacent for sort):
    __half*         xp16    = (__half*)(ws + 0);          // 8100*148*2 = 2,397,600
    __half*         yp16    = (__half*)(ws + 2397600);    // 2,397,600
    float*          pxT     = (float*)(ws + 4795200);     // 256*8100*4 = 8,294,400
    float*          pyT     = (float*)(ws + 13089600);    // 8,294,400
    unsigned short* rx      = (unsigned short*)(ws + 21384000);  // 4,147,200
    unsigned short* iy      = (unsigned short*)(ws + 25531200);  // 4,147,200
    unsigned short* partner = (unsigned short*)(ws + 29678400);  // 4,147,200
    // total: 33,825,600 bytes
    float* out = (float*)d_out;

    hipLaunchKernelGGL(patch_proj_kernel, dim3((NPATCH + TN - 1) / TN), dim3(256), 0, stream,
                       x, y, rnd, xp16, yp16, pxT, pyT, out);
    hipLaunchKernelGGL(sort_kernel, dim3(2 * NPROJ), dim3(SORT_T), 0, stream,
                       pxT, rx, iy);
    hipLaunchKernelGGL(partner_kernel, dim3(NPROJ, 4), dim3(256), 0, stream,
                       rx, iy, partner);
    hipLaunchKernelGGL(reduce_kernel, dim3(NPROJ, 16), dim3(256), 0, stream,
                       xp16, yp16, partner, out);
}

// Round 4
// 360.598 us; speedup vs baseline: 2.1463x; 1.2198x over previous
//
#include <hip/hip_runtime.h>
#include <hip/hip_fp16.h>

#define HH 96
#define WW 96
#define OH 90
#define OW 90
#define NPATCH 8100
#define DD 147
#define DPAD 148
#define NPROJ 256
#define TN 32
#define SORT_N 8192
#define SORT_T 512
#define EPT 16
#define RCH 8          // reduce: chunks per projection
#define KPB 1016       // rows per reduce block (multiple of 4; 8*1016 >= 8100)

union Pack16 { float4 f; __half2 h[4]; };

// ---------------------------------------------------------------------------
// Kernel A: extract patches (Unfold layout f = c*49 + di*7 + dj), materialize
// fp16 gather copies in split layout: main [N][128] + tail [N][32] (halves;
// tail = d 128..146 + zero pad), and compute projections pxT/pyT [256, N]
// (transposed, adjacent in ws so sort indexes them as one [512, N] array).
// std-normalization of rand is skipped: positive per-column scale cannot
// change the per-column argsort.
// ---------------------------------------------------------------------------
__global__ __launch_bounds__(256)
void patch_proj_kernel(const float* __restrict__ x, const float* __restrict__ y,
                       const float* __restrict__ rnd,
                       __half* __restrict__ xmain, __half* __restrict__ ymain,
                       __half* __restrict__ xtail, __half* __restrict__ ytail,
                       float* __restrict__ pxT, float* __restrict__ pyT,
                       float* __restrict__ out)
{
    __shared__ float sx[TN * DPAD];
    __shared__ float sy[TN * DPAD];
    const int tid = threadIdx.x;
    const int n0 = blockIdx.x * TN;
    if (blockIdx.x == 0 && tid == 0) out[0] = 0.0f;  // reduce runs later in stream

    // stage patch tile into LDS (pad col d=147 and OOB rows = 0)
    for (int idx = tid; idx < TN * DPAD; idx += 256) {
        const int t = idx / DPAD;
        const int d = idx - t * DPAD;
        const int n = n0 + t;
        float vx = 0.f, vy = 0.f;
        if (n < NPATCH && d < DD) {
            const int oy = n / OW, ox = n - oy * OW;
            const int c  = d / 49, r  = d - c * 49;
            const int di = r / 7,  dj = r - di * 7;
            const int off = c * (HH * WW) + (oy + di) * WW + (ox + dj);
            vx = x[off];
            vy = y[off];
        }
        sx[idx] = vx;
        sy[idx] = vy;
    }
    __syncthreads();

    // write fp16 split-layout gather copies (half2 stores)
    for (int idx = tid; idx < TN * 80; idx += 256) {
        const int t = idx / 80;
        const int u = idx - t * 80;
        const int n = n0 + t;
        if (n >= NPATCH) continue;
        if (u < 64) {
            const int d = 2 * u;
            ((__half2*)xmain)[(size_t)n * 64 + u] =
                __floats2half2_rn(sx[t * DPAD + d], sx[t * DPAD + d + 1]);
            ((__half2*)ymain)[(size_t)n * 64 + u] =
                __floats2half2_rn(sy[t * DPAD + d], sy[t * DPAD + d + 1]);
        } else {
            const int ut = u - 64;
            const int d = 128 + 2 * ut;
            const float ax0 = (d     < DPAD) ? sx[t * DPAD + d]     : 0.f;
            const float ax1 = (d + 1 < DPAD) ? sx[t * DPAD + d + 1] : 0.f;
            const float ay0 = (d     < DPAD) ? sy[t * DPAD + d]     : 0.f;
            const float ay1 = (d + 1 < DPAD) ? sy[t * DPAD + d + 1] : 0.f;
            ((__half2*)xtail)[(size_t)n * 16 + ut] = __floats2half2_rn(ax0, ax1);
            ((__half2*)ytail)[(size_t)n * 16 + ut] = __floats2half2_rn(ay0, ay1);
        }
    }

    const int p = tid;  // one projection per thread
    float accx[TN], accy[TN];
#pragma unroll
    for (int t = 0; t < TN; ++t) { accx[t] = 0.f; accy[t] = 0.f; }

    for (int d = 0; d < 144; d += 4) {
        const float r0 = rnd[(d + 0) * NPROJ + p];
        const float r1 = rnd[(d + 1) * NPROJ + p];
        const float r2 = rnd[(d + 2) * NPROJ + p];
        const float r3 = rnd[(d + 3) * NPROJ + p];
#pragma unroll
        for (int t = 0; t < TN; ++t) {
            const float4 xv = *(const float4*)&sx[t * DPAD + d];
            const float4 yv = *(const float4*)&sy[t * DPAD + d];
            accx[t] += xv.x * r0 + xv.y * r1 + xv.z * r2 + xv.w * r3;
            accy[t] += yv.x * r0 + yv.y * r1 + yv.z * r2 + yv.w * r3;
        }
    }
    {
        const float r0 = rnd[144 * NPROJ + p];
        const float r1 = rnd[145 * NPROJ + p];
        const float r2 = rnd[146 * NPROJ + p];
#pragma unroll
        for (int t = 0; t < TN; ++t) {
            const float4 xv = *(const float4*)&sx[t * DPAD + 144];
            const float4 yv = *(const float4*)&sy[t * DPAD + 144];
            accx[t] += xv.x * r0 + xv.y * r1 + xv.z * r2;
            accy[t] += yv.x * r0 + yv.y * r1 + yv.z * r2;
        }
    }
#pragma unroll
    for (int t = 0; t < TN; ++t) {
        const int n = n0 + t;
        if (n < NPATCH) {
            pxT[(size_t)p * NPATCH + n] = accx[t];
            pyT[(size_t)p * NPATCH + n] = accy[t];
        }
    }
}

// ---------------------------------------------------------------------------
// Kernel B: per-column argsort via hybrid register/LDS bitonic sort of 8192
// packed u64 keys (order-preserving f32 transform << 13 | index = stable).
// 512 threads x 16 elems/thread: passes with j<16 run in registers (one LDS
// session per merge level); only j>=16 passes touch LDS. blockIdx.x in
// [0,512): cols of pxT (write RANK array rx[idx]=k, scattered) then pyT
// (write iy[k]=idx, sequential).
// ---------------------------------------------------------------------------
__global__ __launch_bounds__(SORT_T, 4)
void sort_kernel(const float* __restrict__ pT,
                 unsigned short* __restrict__ rxOut,
                 unsigned short* __restrict__ iyOut)
{
    __shared__ unsigned long long sk[SORT_N];  // 64 KB
    const int pb = blockIdx.x;
    const int tid = threadIdx.x;
    const float* col = pT + (size_t)pb * NPATCH;

    for (int i = tid; i < SORT_N; i += SORT_T) {
        unsigned long long v;
        if (i < NPATCH) {
            const unsigned u = __float_as_uint(col[i]);
            const unsigned s = (u & 0x80000000u) ? ~u : (u | 0x80000000u);
            v = ((unsigned long long)s << 13) | (unsigned)i;
        } else {
            v = ~0ull;  // +inf pad, strictly greater than any finite key
        }
        sk[i] = v;
    }
    __syncthreads();

    const int base = tid * EPT;
    unsigned long long r[EPT];

#pragma unroll
    for (int q = 0; q < EPT; ++q) r[q] = sk[base + q];
#pragma unroll
    for (int k2 = 2; k2 <= EPT; k2 <<= 1) {
#pragma unroll
        for (int j = k2 >> 1; j > 0; j >>= 1) {
#pragma unroll
            for (int q = 0; q < EPT; ++q) {
                const int l = q ^ j;
                if (l > q) {
                    const bool up = (((base + q) & k2) == 0);
                    const unsigned long long a = r[q], b = r[l];
                    if ((a > b) == up) { r[q] = b; r[l] = a; }
                }
            }
        }
    }
#pragma unroll
    for (int q = 0; q < EPT; ++q) sk[base + q] = r[q];

    for (int k2 = 32; k2 <= SORT_N; k2 <<= 1) {
        for (int j = k2 >> 1; j >= EPT; j >>= 1) {
            __syncthreads();
            const int jm = j - 1;
#pragma unroll
            for (int t = 0; t < SORT_N / 2 / SORT_T; ++t) {
                const int pid = tid + t * SORT_T;
                const int i = ((pid & ~jm) << 1) | (pid & jm);
                const int l = i | j;
                const unsigned long long a = sk[i];
                const unsigned long long b = sk[l];
                const bool up = ((i & k2) == 0);
                if ((a > b) == up) { sk[i] = b; sk[l] = a; }
            }
        }
        __syncthreads();
        const bool up = ((base & k2) == 0);  // uniform across chunk (k2 >= 32)
#pragma unroll
        for (int q = 0; q < EPT; ++q) r[q] = sk[base + q];
#pragma unroll
        for (int j = EPT / 2; j > 0; j >>= 1) {
#pragma unroll
            for (int q = 0; q < EPT; ++q) {
                const int l = q ^ j;
                if (l > q) {
                    const unsigned long long a = r[q], b = r[l];
                    if ((a > b) == up) { r[q] = b; r[l] = a; }
                }
            }
        }
        if (k2 < SORT_N) {
#pragma unroll
            for (int q = 0; q < EPT; ++q) sk[base + q] = r[q];
        }
    }

    if (pb < NPROJ) {
        unsigned short* rk = rxOut + (size_t)pb * NPATCH;
#pragma unroll
        for (int q = 0; q < EPT; ++q) {
            const int idx = (int)(r[q] & 0x1FFFu);
            if (idx < NPATCH) rk[idx] = (unsigned short)(base + q);
        }
    } else {
        unsigned short* io = iyOut + (size_t)(pb - NPROJ) * NPATCH;
#pragma unroll
        for (int q = 0; q < EPT; ++q) {
            if (base + q < NPATCH) io[base + q] = (unsigned short)(r[q] & 0x1FFFu);
        }
    }
}

// ---------------------------------------------------------------------------
// Kernel B2: partner[p][i] = iy[p][ rx[p][i] ].
// ---------------------------------------------------------------------------
__global__ __launch_bounds__(256)
void partner_kernel(const unsigned short* __restrict__ rx,
                    const unsigned short* __restrict__ iy,
                    unsigned short* __restrict__ partner)
{
    const int p = blockIdx.x;
    const int ipb = (NPATCH + gridDim.y - 1) / gridDim.y;
    const int i0 = blockIdx.y * ipb;
    const int iend = min(i0 + ipb, NPATCH);
    const unsigned short* rxp = rx + (size_t)p * NPATCH;
    const unsigned short* iyp = iy + (size_t)p * NPATCH;
    unsigned short* pp = partner + (size_t)p * NPATCH;
    for (int i = i0 + threadIdx.x; i < iend; i += 256)
        pp[i] = iyp[rxp[i]];
}

// ---------------------------------------------------------------------------
// Kernel C: loss = mean over (p, i, d) of |xp[i, d] - yp[partner[p][i], d]|.
// Main pass: 4 rows per wave-iteration; x-load = one coalesced dwordx4 over 4
// consecutive rows (1 KiB/wave), y-load = dwordx4 with 16-lane groups per
// random row. Partner index prefetched one iteration ahead. Packed-fp16
// sub/abs/add (3 VALU per 2 elems), fp32 only at final reduction.
// Tail pass: 16 rows per wave-iteration on the 32-half tail arrays.
// ---------------------------------------------------------------------------
__global__ __launch_bounds__(256)
void reduce_kernel(const __half* __restrict__ xmain, const __half* __restrict__ ymain,
                   const __half* __restrict__ xtail, const __half* __restrict__ ytail,
                   const unsigned short* __restrict__ partner,
                   float* __restrict__ out)
{
    const int p = blockIdx.x;
    const int i0 = blockIdx.y * KPB;
    const int iend = min(i0 + KPB, NPATCH);
    const int tid = threadIdx.x;
    const int wave = tid >> 6, lane = tid & 63;
    const unsigned short* par = partner + (size_t)p * NPATCH;

    __half2 a0 = __float2half2_rn(0.f), a1 = a0, a2 = a0, a3 = a0;

    // ---- main pass: d = 0..127 ----
    {
        const int g = lane >> 4;   // row within quad
        const int u = lane & 15;   // 16B unit within row
        int i = i0 + wave * 4;
        if (i < iend) {
            int j = par[i + g];
            for (; i < iend; i += 16) {
                const int pi = min(i + 16 + g, NPATCH - 1);  // prefetch (clamped)
                const int jn = par[pi];
                Pack16 xa, ya;
                xa.f = ((const float4*)xmain)[(size_t)i * 16 + lane];
                ya.f = ((const float4*)ymain)[(size_t)j * 16 + u];
                a0 = __hadd2(a0, __habs2(__hsub2(xa.h[0], ya.h[0])));
                a1 = __hadd2(a1, __habs2(__hsub2(xa.h[1], ya.h[1])));
                a2 = __hadd2(a2, __habs2(__hsub2(xa.h[2], ya.h[2])));
                a3 = __hadd2(a3, __habs2(__hsub2(xa.h[3], ya.h[3])));
                j = jn;
            }
        }
    }

    // ---- tail pass: d = 128..146 (+ zero pad to 160) ----
    {
        const int g2 = lane >> 2;  // row within 16-row group
        const int u2 = lane & 3;   // 16B unit within tail row
        for (int i2 = i0 + wave * 16; i2 < iend; i2 += 64) {
            const int r = i2 + g2;
            if (r < iend) {
                const int j = par[r];
                Pack16 xa, ya;
                xa.f = ((const float4*)xtail)[(size_t)i2 * 4 + lane];
                ya.f = ((const float4*)ytail)[(size_t)j * 4 + u2];
                a0 = __hadd2(a0, __habs2(__hsub2(xa.h[0], ya.h[0])));
                a1 = __hadd2(a1, __habs2(__hsub2(xa.h[1], ya.h[1])));
                a2 = __hadd2(a2, __habs2(__hsub2(xa.h[2], ya.h[2])));
                a3 = __hadd2(a3, __habs2(__hsub2(xa.h[3], ya.h[3])));
            }
        }
    }

    const float2 f0 = __half22float2(a0);
    const float2 f1 = __half22float2(a1);
    const float2 f2 = __half22float2(a2);
    const float2 f3 = __half22float2(a3);
    float acc = f0.x + f0.y + f1.x + f1.y + f2.x + f2.y + f3.x + f3.y;

#pragma unroll
    for (int o = 32; o > 0; o >>= 1) acc += __shfl_down(acc, o, 64);

    __shared__ float sred[4];
    if (lane == 0) sred[wave] = acc;
    __syncthreads();
    if (tid == 0) {
        const float s = sred[0] + sred[1] + sred[2] + sred[3];
        atomicAdd(out, s * (1.0f / ((float)NPROJ * (float)NPATCH * (float)DD)));
    }
}

// ---------------------------------------------------------------------------
extern "C" void kernel_launch(void* const* d_in, const int* in_sizes, int n_in,
                              void* d_out, int out_size, void* d_ws, size_t ws_size,
                              hipStream_t stream)
{
    const float* x   = (const float*)d_in[0];
    const float* y   = (const float*)d_in[1];
    const float* rnd = (const float*)d_in[2];

    char* ws = (char*)d_ws;
    // workspace layout (16B-aligned; pxT|pyT adjacent for sort; partner
    // aliases pxT — pxT is dead once sort_kernel has run):
    __half* xmain = (__half*)(ws + 0);          // 8100*128*2 = 2,073,600
    __half* ymain = (__half*)(ws + 2073600);    // 2,073,600
    __half* xtail = (__half*)(ws + 4147200);    // 8100*32*2  =   518,400
    __half* ytail = (__half*)(ws + 4665600);    //               518,400
    float*  pxT   = (float*)(ws + 5184000);     // 256*8100*4 = 8,294,400
    float*  pyT   = (float*)(ws + 13478400);    //             8,294,400
    unsigned short* rx      = (unsigned short*)(ws + 21772800);  // 4,147,200
    unsigned short* iy      = (unsigned short*)(ws + 25920000);  // 4,147,200
    unsigned short* partner = (unsigned short*)(ws + 5184000);   // alias pxT
    // high-water: 30,067,200 bytes
    float* out = (float*)d_out;

    hipLaunchKernelGGL(patch_proj_kernel, dim3((NPATCH + TN - 1) / TN), dim3(256), 0, stream,
                       x, y, rnd, xmain, ymain, xtail, ytail, pxT, pyT, out);
    hipLaunchKernelGGL(sort_kernel, dim3(2 * NPROJ), dim3(SORT_T), 0, stream,
                       pxT, rx, iy);
    hipLaunchKernelGGL(partner_kernel, dim3(NPROJ, 4), dim3(256), 0, stream,
                       rx, iy, partner);
    hipLaunchKernelGGL(reduce_kernel, dim3(NPROJ, RCH), dim3(256), 0, stream,
                       xmain, ymain, xtail, ytail, partner, out);
}

// Round 5
// 311.870 us; speedup vs baseline: 2.4817x; 1.1562x over previous
//
#include <hip/hip_runtime.h>
#include <hip/hip_fp16.h>

#define HH 96
#define WW 96
#define OH 90
#define OW 90
#define NPATCH 8100
#define DD 147
#define DPAD 148
#define NPROJ 256
#define TN 32
#define SORT_N 8192
#define SORT_T 512
#define EPT 16
#define RCH 8          // reduce: chunks per projection
#define KPB 1016       // rows per reduce block (multiple of 4; 8*1016 >= 8100)

// physical LDS slot for logical index i: XOR-swizzle low 4 bits with bits 4..7
// -> a thread's contiguous 16-chunk spans all 16 bank-pairs (kills the 32-way
// conflict of the tid*16 layout), strided session reads stay conflict-free.
#define PHI(i) ((i) ^ (((i) >> 4) & 15))

union Pack16 { float4 f; __half2 h[4]; };

__device__ __forceinline__ void cswap(unsigned long long& a, unsigned long long& b, bool up) {
    if ((a > b) == up) { unsigned long long t = a; a = b; b = t; }
}

// ---------------------------------------------------------------------------
// Kernel A: extract patches (Unfold layout f = c*49 + di*7 + dj), materialize
// fp16 gather copies in split layout: main [N][128] + tail [N][32] (halves;
// tail = d 128..146 + zero pad), and compute projections pxT/pyT [256, N]
// (transposed, adjacent in ws so sort indexes them as one [512, N] array).
// std-normalization of rand is skipped: positive per-column scale cannot
// change the per-column argsort.
// ---------------------------------------------------------------------------
__global__ __launch_bounds__(256)
void patch_proj_kernel(const float* __restrict__ x, const float* __restrict__ y,
                       const float* __restrict__ rnd,
                       __half* __restrict__ xmain, __half* __restrict__ ymain,
                       __half* __restrict__ xtail, __half* __restrict__ ytail,
                       float* __restrict__ pxT, float* __restrict__ pyT,
                       float* __restrict__ out)
{
    __shared__ float sx[TN * DPAD];
    __shared__ float sy[TN * DPAD];
    const int tid = threadIdx.x;
    const int n0 = blockIdx.x * TN;
    if (blockIdx.x == 0 && tid == 0) out[0] = 0.0f;  // reduce runs later in stream

    for (int idx = tid; idx < TN * DPAD; idx += 256) {
        const int t = idx / DPAD;
        const int d = idx - t * DPAD;
        const int n = n0 + t;
        float vx = 0.f, vy = 0.f;
        if (n < NPATCH && d < DD) {
            const int oy = n / OW, ox = n - oy * OW;
            const int c  = d / 49, r  = d - c * 49;
            const int di = r / 7,  dj = r - di * 7;
            const int off = c * (HH * WW) + (oy + di) * WW + (ox + dj);
            vx = x[off];
            vy = y[off];
        }
        sx[idx] = vx;
        sy[idx] = vy;
    }
    __syncthreads();

    for (int idx = tid; idx < TN * 80; idx += 256) {
        const int t = idx / 80;
        const int u = idx - t * 80;
        const int n = n0 + t;
        if (n >= NPATCH) continue;
        if (u < 64) {
            const int d = 2 * u;
            ((__half2*)xmain)[(size_t)n * 64 + u] =
                __floats2half2_rn(sx[t * DPAD + d], sx[t * DPAD + d + 1]);
            ((__half2*)ymain)[(size_t)n * 64 + u] =
                __floats2half2_rn(sy[t * DPAD + d], sy[t * DPAD + d + 1]);
        } else {
            const int ut = u - 64;
            const int d = 128 + 2 * ut;
            const float ax0 = (d     < DPAD) ? sx[t * DPAD + d]     : 0.f;
            const float ax1 = (d + 1 < DPAD) ? sx[t * DPAD + d + 1] : 0.f;
            const float ay0 = (d     < DPAD) ? sy[t * DPAD + d]     : 0.f;
            const float ay1 = (d + 1 < DPAD) ? sy[t * DPAD + d + 1] : 0.f;
            ((__half2*)xtail)[(size_t)n * 16 + ut] = __floats2half2_rn(ax0, ax1);
            ((__half2*)ytail)[(size_t)n * 16 + ut] = __floats2half2_rn(ay0, ay1);
        }
    }

    const int p = tid;  // one projection per thread
    float accx[TN], accy[TN];
#pragma unroll
    for (int t = 0; t < TN; ++t) { accx[t] = 0.f; accy[t] = 0.f; }

    for (int d = 0; d < 144; d += 4) {
        const float r0 = rnd[(d + 0) * NPROJ + p];
        const float r1 = rnd[(d + 1) * NPROJ + p];
        const float r2 = rnd[(d + 2) * NPROJ + p];
        const float r3 = rnd[(d + 3) * NPROJ + p];
#pragma unroll
        for (int t = 0; t < TN; ++t) {
            const float4 xv = *(const float4*)&sx[t * DPAD + d];
            const float4 yv = *(const float4*)&sy[t * DPAD + d];
            accx[t] += xv.x * r0 + xv.y * r1 + xv.z * r2 + xv.w * r3;
            accy[t] += yv.x * r0 + yv.y * r1 + yv.z * r2 + yv.w * r3;
        }
    }
    {
        const float r0 = rnd[144 * NPROJ + p];
        const float r1 = rnd[145 * NPROJ + p];
        const float r2 = rnd[146 * NPROJ + p];
#pragma unroll
        for (int t = 0; t < TN; ++t) {
            const float4 xv = *(const float4*)&sx[t * DPAD + 144];
            const float4 yv = *(const float4*)&sy[t * DPAD + 144];
            accx[t] += xv.x * r0 + xv.y * r1 + xv.z * r2;
            accy[t] += yv.x * r0 + yv.y * r1 + yv.z * r2;
        }
    }
#pragma unroll
    for (int t = 0; t < TN; ++t) {
        const int n = n0 + t;
        if (n < NPATCH) {
            pxT[(size_t)p * NPATCH + n] = accx[t];
            pyT[(size_t)p * NPATCH + n] = accy[t];
        }
    }
}

// ---------------------------------------------------------------------------
// Kernel B: per-column argsort via hybrid register/LDS bitonic sort of 8192
// packed u64 keys (order-preserving f32 transform << 13 | index = stable).
// v3: XOR-swizzled LDS layout (PHI) kills the 32-way chunk conflicts; up to
// 3 bitonic levels fused per LDS session (8 strided elems in registers, 12
// cswaps) -> LDS traffic ~10 MB -> ~3.8 MB per block, 45 -> ~29 barriers.
// blockIdx.x in [0,512): cols of pxT (write RANK rx[idx]=k, scattered) then
// pyT (write iy[k]=idx, sequential).
// ---------------------------------------------------------------------------
__global__ __launch_bounds__(SORT_T, 4)
void sort_kernel(const float* __restrict__ pT,
                 unsigned short* __restrict__ rxOut,
                 unsigned short* __restrict__ iyOut)
{
    __shared__ unsigned long long sk[SORT_N];  // 64 KB
    const int pb = blockIdx.x;
    const int tid = threadIdx.x;
    const float* col = pT + (size_t)pb * NPATCH;

    for (int i = tid; i < SORT_N; i += SORT_T) {
        unsigned long long v;
        if (i < NPATCH) {
            const unsigned u = __float_as_uint(col[i]);
            const unsigned s = (u & 0x80000000u) ? ~u : (u | 0x80000000u);
            v = ((unsigned long long)s << 13) | (unsigned)i;
        } else {
            v = ~0ull;  // +inf pad, strictly greater than any finite key
        }
        sk[PHI(i)] = v;
    }
    __syncthreads();

    const int base = tid * EPT;
    const int sw = tid & 15;  // chunk-local swizzle: slot = base | (q ^ sw)
    unsigned long long r[EPT];

    // k2 = 2..16 entirely in registers
#pragma unroll
    for (int q = 0; q < EPT; ++q) r[q] = sk[base | (q ^ sw)];
#pragma unroll
    for (int k2 = 2; k2 <= EPT; k2 <<= 1) {
#pragma unroll
        for (int j = k2 >> 1; j > 0; j >>= 1) {
#pragma unroll
            for (int q = 0; q < EPT; ++q) {
                const int l = q ^ j;
                if (l > q) {
                    const bool up = (((base + q) & k2) == 0);
                    cswap(r[q], r[l], up);
                }
            }
        }
    }
#pragma unroll
    for (int q = 0; q < EPT; ++q) sk[base | (q ^ sw)] = r[q];

    for (int k2 = 32; k2 <= SORT_N; k2 <<= 1) {
        int j = k2 >> 1;
        while (j >= EPT) {
            __syncthreads();
            const int lj = 31 - __clz(j);
            const int L = lj - 3;  // levels >= 16 remaining (incl. j)
            if (L >= 3) {          // fuse strides j, j/2, j/4  (s = j/4)
                const int ls = lj - 2;
                const int sm = (1 << ls) - 1;
#pragma unroll
                for (int gg = 0; gg < SORT_N / 8 / SORT_T; ++gg) {
                    const int g = tid + gg * SORT_T;
                    const int b = ((g >> ls) << (ls + 3)) | (g & sm);
                    unsigned long long e[8];
#pragma unroll
                    for (int t = 0; t < 8; ++t) e[t] = sk[PHI(b + (t << ls))];
                    const bool up = ((b & k2) == 0);
                    cswap(e[0], e[4], up); cswap(e[1], e[5], up);
                    cswap(e[2], e[6], up); cswap(e[3], e[7], up);
                    cswap(e[0], e[2], up); cswap(e[1], e[3], up);
                    cswap(e[4], e[6], up); cswap(e[5], e[7], up);
                    cswap(e[0], e[1], up); cswap(e[2], e[3], up);
                    cswap(e[4], e[5], up); cswap(e[6], e[7], up);
#pragma unroll
                    for (int t = 0; t < 8; ++t) sk[PHI(b + (t << ls))] = e[t];
                }
                j >>= 3;
            } else if (L == 2) {   // fuse strides j, j/2  (s = j/2)
                const int ls = lj - 1;
                const int sm = (1 << ls) - 1;
#pragma unroll
                for (int gg = 0; gg < SORT_N / 4 / SORT_T; ++gg) {
                    const int g = tid + gg * SORT_T;
                    const int b = ((g >> ls) << (ls + 2)) | (g & sm);
                    unsigned long long e[4];
#pragma unroll
                    for (int t = 0; t < 4; ++t) e[t] = sk[PHI(b + (t << ls))];
                    const bool up = ((b & k2) == 0);
                    cswap(e[0], e[2], up); cswap(e[1], e[3], up);
                    cswap(e[0], e[1], up); cswap(e[2], e[3], up);
#pragma unroll
                    for (int t = 0; t < 4; ++t) sk[PHI(b + (t << ls))] = e[t];
                }
                j >>= 2;
            } else {               // single pair pass at stride j
                const int ls = lj;
                const int sm = j - 1;
#pragma unroll
                for (int gg = 0; gg < SORT_N / 2 / SORT_T; ++gg) {
                    const int g = tid + gg * SORT_T;
                    const int b = ((g >> ls) << (ls + 1)) | (g & sm);
                    unsigned long long a = sk[PHI(b)];
                    unsigned long long c = sk[PHI(b + j)];
                    const bool up = ((b & k2) == 0);
                    cswap(a, c, up);
                    sk[PHI(b)] = a;
                    sk[PHI(b + j)] = c;
                }
                j >>= 1;
            }
        }
        __syncthreads();
        const bool up = ((base & k2) == 0);  // uniform per chunk (k2 >= 32)
#pragma unroll
        for (int q = 0; q < EPT; ++q) r[q] = sk[base | (q ^ sw)];
#pragma unroll
        for (int j2 = EPT / 2; j2 > 0; j2 >>= 1) {
#pragma unroll
            for (int q = 0; q < EPT; ++q) {
                const int l = q ^ j2;
                if (l > q) cswap(r[q], r[l], up);
            }
        }
        if (k2 < SORT_N) {
#pragma unroll
            for (int q = 0; q < EPT; ++q) sk[base | (q ^ sw)] = r[q];
        }
    }

    // outputs straight from registers (pads sort to tail: real ranks 0..8099)
    if (pb < NPROJ) {
        unsigned short* rk = rxOut + (size_t)pb * NPATCH;
#pragma unroll
        for (int q = 0; q < EPT; ++q) {
            const int idx = (int)(r[q] & 0x1FFFu);
            if (idx < NPATCH) rk[idx] = (unsigned short)(base + q);
        }
    } else {
        unsigned short* io = iyOut + (size_t)(pb - NPROJ) * NPATCH;
#pragma unroll
        for (int q = 0; q < EPT; ++q) {
            if (base + q < NPATCH) io[base + q] = (unsigned short)(r[q] & 0x1FFFu);
        }
    }
}

// ---------------------------------------------------------------------------
// Kernel B2: partner[p][i] = iy[p][ rx[p][i] ].
// ---------------------------------------------------------------------------
__global__ __launch_bounds__(256)
void partner_kernel(const unsigned short* __restrict__ rx,
                    const unsigned short* __restrict__ iy,
                    unsigned short* __restrict__ partner)
{
    const int p = blockIdx.x;
    const int ipb = (NPATCH + gridDim.y - 1) / gridDim.y;
    const int i0 = blockIdx.y * ipb;
    const int iend = min(i0 + ipb, NPATCH);
    const unsigned short* rxp = rx + (size_t)p * NPATCH;
    const unsigned short* iyp = iy + (size_t)p * NPATCH;
    unsigned short* pp = partner + (size_t)p * NPATCH;
    for (int i = i0 + threadIdx.x; i < iend; i += 256)
        pp[i] = iyp[rxp[i]];
}

// ---------------------------------------------------------------------------
// Kernel C: loss = mean over (p, i, d) of |xp[i, d] - yp[partner[p][i], d]|.
// Main pass: 4 rows per wave-iteration; x-load = one coalesced dwordx4 over 4
// consecutive rows (1 KiB/wave), y-load = dwordx4 with 16-lane groups per
// random row. Partner index prefetched one iteration ahead. Packed-fp16
// sub/abs/add, fp32 only at final reduction.
// ---------------------------------------------------------------------------
__global__ __launch_bounds__(256)
void reduce_kernel(const __half* __restrict__ xmain, const __half* __restrict__ ymain,
                   const __half* __restrict__ xtail, const __half* __restrict__ ytail,
                   const unsigned short* __restrict__ partner,
                   float* __restrict__ out)
{
    const int p = blockIdx.x;
    const int i0 = blockIdx.y * KPB;
    const int iend = min(i0 + KPB, NPATCH);
    const int tid = threadIdx.x;
    const int wave = tid >> 6, lane = tid & 63;
    const unsigned short* par = partner + (size_t)p * NPATCH;

    __half2 a0 = __float2half2_rn(0.f), a1 = a0, a2 = a0, a3 = a0;

    // ---- main pass: d = 0..127 ----
    {
        const int g = lane >> 4;   // row within quad
        const int u = lane & 15;   // 16B unit within row
        int i = i0 + wave * 4;
        if (i < iend) {
            int j = par[i + g];
            for (; i < iend; i += 16) {
                const int pi = min(i + 16 + g, NPATCH - 1);  // prefetch (clamped)
                const int jn = par[pi];
                Pack16 xa, ya;
                xa.f = ((const float4*)xmain)[(size_t)i * 16 + lane];
                ya.f = ((const float4*)ymain)[(size_t)j * 16 + u];
                a0 = __hadd2(a0, __habs2(__hsub2(xa.h[0], ya.h[0])));
                a1 = __hadd2(a1, __habs2(__hsub2(xa.h[1], ya.h[1])));
                a2 = __hadd2(a2, __habs2(__hsub2(xa.h[2], ya.h[2])));
                a3 = __hadd2(a3, __habs2(__hsub2(xa.h[3], ya.h[3])));
                j = jn;
            }
        }
    }

    // ---- tail pass: d = 128..146 (+ zero pad to 160) ----
    {
        const int g2 = lane >> 2;  // row within 16-row group
        const int u2 = lane & 3;   // 16B unit within tail row
        for (int i2 = i0 + wave * 16; i2 < iend; i2 += 64) {
            const int r = i2 + g2;
            if (r < iend) {
                const int j = par[r];
                Pack16 xa, ya;
                xa.f = ((const float4*)xtail)[(size_t)i2 * 4 + lane];
                ya.f = ((const float4*)ytail)[(size_t)j * 4 + u2];
                a0 = __hadd2(a0, __habs2(__hsub2(xa.h[0], ya.h[0])));
                a1 = __hadd2(a1, __habs2(__hsub2(xa.h[1], ya.h[1])));
                a2 = __hadd2(a2, __habs2(__hsub2(xa.h[2], ya.h[2])));
                a3 = __hadd2(a3, __habs2(__hsub2(xa.h[3], ya.h[3])));
            }
        }
    }

    const float2 f0 = __half22float2(a0);
    const float2 f1 = __half22float2(a1);
    const float2 f2 = __half22float2(a2);
    const float2 f3 = __half22float2(a3);
    float acc = f0.x + f0.y + f1.x + f1.y + f2.x + f2.y + f3.x + f3.y;

#pragma unroll
    for (int o = 32; o > 0; o >>= 1) acc += __shfl_down(acc, o, 64);

    __shared__ float sred[4];
    if (lane == 0) sred[wave] = acc;
    __syncthreads();
    if (tid == 0) {
        const float s = sred[0] + sred[1] + sred[2] + sred[3];
        atomicAdd(out, s * (1.0f / ((float)NPROJ * (float)NPATCH * (float)DD)));
    }
}

// ---------------------------------------------------------------------------
extern "C" void kernel_launch(void* const* d_in, const int* in_sizes, int n_in,
                              void* d_out, int out_size, void* d_ws, size_t ws_size,
                              hipStream_t stream)
{
    const float* x   = (const float*)d_in[0];
    const float* y   = (const float*)d_in[1];
    const float* rnd = (const float*)d_in[2];

    char* ws = (char*)d_ws;
    // workspace layout (16B-aligned; pxT|pyT adjacent for sort; partner
    // aliases pxT — pxT is dead once sort_kernel has run):
    __half* xmain = (__half*)(ws + 0);          // 8100*128*2 = 2,073,600
    __half* ymain = (__half*)(ws + 2073600);    // 2,073,600
    __half* xtail = (__half*)(ws + 4147200);    // 8100*32*2  =   518,400
    __half* ytail = (__half*)(ws + 4665600);    //               518,400
    float*  pxT   = (float*)(ws + 5184000);     // 256*8100*4 = 8,294,400
    float*  pyT   = (float*)(ws + 13478400);    //             8,294,400
    unsigned short* rx      = (unsigned short*)(ws + 21772800);  // 4,147,200
    unsigned short* iy      = (unsigned short*)(ws + 25920000);  // 4,147,200
    unsigned short* partner = (unsigned short*)(ws + 5184000);   // alias pxT
    // high-water: 30,067,200 bytes
    float* out = (float*)d_out;

    hipLaunchKernelGGL(patch_proj_kernel, dim3((NPATCH + TN - 1) / TN), dim3(256), 0, stream,
                       x, y, rnd, xmain, ymain, xtail, ytail, pxT, pyT, out);
    hipLaunchKernelGGL(sort_kernel, dim3(2 * NPROJ), dim3(SORT_T), 0, stream,
                       pxT, rx, iy);
    hipLaunchKernelGGL(partner_kernel, dim3(NPROJ, 4), dim3(256), 0, stream,
                       rx, iy, partner);
    hipLaunchKernelGGL(reduce_kernel, dim3(NPROJ, RCH), dim3(256), 0, stream,
                       xmain, ymain, xtail, ytail, partner, out);
}

// Round 6
// 238.402 us; speedup vs baseline: 3.2465x; 1.3082x over previous
//
#include <hip/hip_runtime.h>
#include <hip/hip_fp16.h>

#define HH 96
#define WW 96
#define OH 90
#define OW 90
#define NPATCH 8100
#define DD 147
#define DPAD 148
#define NPROJ 256
#define TN 32
#define SORT_N 8192
#define SORT_T 512
#define EPT 16
#define RCH 8          // reduce: chunks per projection
#define KPB 1016       // rows per reduce block (multiple of 4; 8*1016 >= 8100)

// physical LDS slot for logical index i: XOR-swizzle low 4 bits with bits 4..7
#define PHI(i) ((i) ^ (((i) >> 4) & 15))

union Pack16 { float4 f; __half2 h[4]; };

__device__ __forceinline__ void cswap(unsigned long long& a, unsigned long long& b, bool up) {
    if ((a > b) == up) { unsigned long long t = a; a = b; b = t; }
}

// ---------------------------------------------------------------------------
// Kernel A (v3): one image per block (blockIdx.y selects x/y) -> grid 254x2.
// Stage 32x148 f32 patch tile in LDS (Unfold layout f = c*49+di*7+dj), write
// fp16 split gather copies (main 128 + tail 32), then project: thread
// (q=tid&63, th=tid>>6) computes 8 patches x 4 projections; the patch b128
// LDS read is wave-uniform (broadcast, conflict-free) and feeds 16 FMAs;
// rnd rows are read as coalesced float4. Epilogue stores are float4 (fixes
// the 131 MB partial-sector write amplification of the scalar-store version).
// std-normalization of rand is skipped: positive per-column scale cannot
// change the per-column argsort.
// ---------------------------------------------------------------------------
__global__ __launch_bounds__(256, 4)
void patch_proj_kernel(const float* __restrict__ x, const float* __restrict__ y,
                       const float* __restrict__ rnd,
                       __half* __restrict__ xmain, __half* __restrict__ ymain,
                       __half* __restrict__ xtail, __half* __restrict__ ytail,
                       float* __restrict__ pxT, float* __restrict__ pyT,
                       float* __restrict__ out)
{
    __shared__ float s[TN * DPAD];
    const int tid = threadIdx.x;
    const int n0 = blockIdx.x * TN;
    const int img = blockIdx.y;
    const float* __restrict__ src = img ? y : x;
    __half* __restrict__ mout = img ? ymain : xmain;
    __half* __restrict__ tout = img ? ytail : xtail;
    float* __restrict__ pT = img ? pyT : pxT;
    if (blockIdx.x == 0 && img == 0 && tid == 0) out[0] = 0.0f;

    // stage patch tile into LDS (pad col d=147 and OOB rows = 0)
    for (int idx = tid; idx < TN * DPAD; idx += 256) {
        const int t = idx / DPAD;
        const int d = idx - t * DPAD;
        const int n = n0 + t;
        float v = 0.f;
        if (n < NPATCH && d < DD) {
            const int oy = n / OW, ox = n - oy * OW;
            const int c  = d / 49, r  = d - c * 49;
            const int di = r / 7,  dj = r - di * 7;
            v = src[c * (HH * WW) + (oy + di) * WW + (ox + dj)];
        }
        s[idx] = v;
    }
    __syncthreads();

    // fp16 split-layout gather copies (half2 stores)
    for (int idx = tid; idx < TN * 80; idx += 256) {
        const int t = idx / 80;
        const int u = idx - t * 80;
        const int n = n0 + t;
        if (n >= NPATCH) continue;
        if (u < 64) {
            const int d = 2 * u;
            ((__half2*)mout)[(size_t)n * 64 + u] =
                __floats2half2_rn(s[t * DPAD + d], s[t * DPAD + d + 1]);
        } else {
            const int ut = u - 64;
            const int d = 128 + 2 * ut;
            const float a0 = (d     < DPAD) ? s[t * DPAD + d]     : 0.f;
            const float a1 = (d + 1 < DPAD) ? s[t * DPAD + d + 1] : 0.f;
            ((__half2*)tout)[(size_t)n * 16 + ut] = __floats2half2_rn(a0, a1);
        }
    }

    // projection: thread covers proj 4q..4q+3, patches n0+t0 .. n0+t0+7
    const int q  = tid & 63;
    const int t0 = (tid >> 6) * 8;
    const float4* __restrict__ rnd4 = (const float4*)rnd;  // [147][64] float4s

    float acc[8][4];
#pragma unroll
    for (int t = 0; t < 8; ++t)
#pragma unroll
        for (int r = 0; r < 4; ++r) acc[t][r] = 0.f;

    for (int d = 0; d < 144; d += 4) {
        const float4 r0 = rnd4[(d + 0) * 64 + q];
        const float4 r1 = rnd4[(d + 1) * 64 + q];
        const float4 r2 = rnd4[(d + 2) * 64 + q];
        const float4 r3 = rnd4[(d + 3) * 64 + q];
#pragma unroll
        for (int t = 0; t < 8; ++t) {
            const float4 v = *(const float4*)&s[(t0 + t) * DPAD + d];
            acc[t][0] += v.x * r0.x + v.y * r1.x + v.z * r2.x + v.w * r3.x;
            acc[t][1] += v.x * r0.y + v.y * r1.y + v.z * r2.y + v.w * r3.y;
            acc[t][2] += v.x * r0.z + v.y * r1.z + v.z * r2.z + v.w * r3.z;
            acc[t][3] += v.x * r0.w + v.y * r1.w + v.z * r2.w + v.w * r3.w;
        }
    }
    {   // tail d = 144..146 (no rnd row 147 exists; v.w unused)
        const float4 r0 = rnd4[144 * 64 + q];
        const float4 r1 = rnd4[145 * 64 + q];
        const float4 r2 = rnd4[146 * 64 + q];
#pragma unroll
        for (int t = 0; t < 8; ++t) {
            const float4 v = *(const float4*)&s[(t0 + t) * DPAD + 144];
            acc[t][0] += v.x * r0.x + v.y * r1.x + v.z * r2.x;
            acc[t][1] += v.x * r0.y + v.y * r1.y + v.z * r2.y;
            acc[t][2] += v.x * r0.z + v.y * r1.z + v.z * r2.z;
            acc[t][3] += v.x * r0.w + v.y * r1.w + v.z * r2.w;
        }
    }

    // epilogue: per projection row, 8 consecutive n -> two float4 stores
    const int nb = n0 + t0;
#pragma unroll
    for (int r = 0; r < 4; ++r) {
        float* row = pT + (size_t)(4 * q + r) * NPATCH + nb;
        if (nb + 7 < NPATCH) {
            float4 lo, hi;
            lo.x = acc[0][r]; lo.y = acc[1][r]; lo.z = acc[2][r]; lo.w = acc[3][r];
            hi.x = acc[4][r]; hi.y = acc[5][r]; hi.z = acc[6][r]; hi.w = acc[7][r];
            ((float4*)row)[0] = lo;
            ((float4*)row)[1] = hi;
        } else {
#pragma unroll
            for (int t = 0; t < 8; ++t)
                if (nb + t < NPATCH) row[t] = acc[t][r];
        }
    }
}

// ---------------------------------------------------------------------------
// Kernel B: per-column argsort via hybrid register/LDS bitonic sort of 8192
// packed u64 keys (order-preserving f32 transform << 13 | index = stable).
// XOR-swizzled LDS layout (PHI); up to 3 bitonic levels fused per session.
// blockIdx.x in [0,512): cols of pxT (write RANK rx[idx]=k) then pyT
// (write iy[k]=idx).
// ---------------------------------------------------------------------------
__global__ __launch_bounds__(SORT_T, 4)
void sort_kernel(const float* __restrict__ pT,
                 unsigned short* __restrict__ rxOut,
                 unsigned short* __restrict__ iyOut)
{
    __shared__ unsigned long long sk[SORT_N];  // 64 KB
    const int pb = blockIdx.x;
    const int tid = threadIdx.x;
    const float* col = pT + (size_t)pb * NPATCH;

    for (int i = tid; i < SORT_N; i += SORT_T) {
        unsigned long long v;
        if (i < NPATCH) {
            const unsigned u = __float_as_uint(col[i]);
            const unsigned s = (u & 0x80000000u) ? ~u : (u | 0x80000000u);
            v = ((unsigned long long)s << 13) | (unsigned)i;
        } else {
            v = ~0ull;  // +inf pad, strictly greater than any finite key
        }
        sk[PHI(i)] = v;
    }
    __syncthreads();

    const int base = tid * EPT;
    const int sw = tid & 15;  // chunk-local swizzle: slot = base | (q ^ sw)
    unsigned long long r[EPT];

    // k2 = 2..16 entirely in registers
#pragma unroll
    for (int q = 0; q < EPT; ++q) r[q] = sk[base | (q ^ sw)];
#pragma unroll
    for (int k2 = 2; k2 <= EPT; k2 <<= 1) {
#pragma unroll
        for (int j = k2 >> 1; j > 0; j >>= 1) {
#pragma unroll
            for (int q = 0; q < EPT; ++q) {
                const int l = q ^ j;
                if (l > q) {
                    const bool up = (((base + q) & k2) == 0);
                    cswap(r[q], r[l], up);
                }
            }
        }
    }
#pragma unroll
    for (int q = 0; q < EPT; ++q) sk[base | (q ^ sw)] = r[q];

    for (int k2 = 32; k2 <= SORT_N; k2 <<= 1) {
        int j = k2 >> 1;
        while (j >= EPT) {
            __syncthreads();
            const int lj = 31 - __clz(j);
            const int L = lj - 3;  // levels >= 16 remaining (incl. j)
            if (L >= 3) {          // fuse strides j, j/2, j/4  (s = j/4)
                const int ls = lj - 2;
                const int sm = (1 << ls) - 1;
#pragma unroll
                for (int gg = 0; gg < SORT_N / 8 / SORT_T; ++gg) {
                    const int g = tid + gg * SORT_T;
                    const int b = ((g >> ls) << (ls + 3)) | (g & sm);
                    unsigned long long e[8];
#pragma unroll
                    for (int t = 0; t < 8; ++t) e[t] = sk[PHI(b + (t << ls))];
                    const bool up = ((b & k2) == 0);
                    cswap(e[0], e[4], up); cswap(e[1], e[5], up);
                    cswap(e[2], e[6], up); cswap(e[3], e[7], up);
                    cswap(e[0], e[2], up); cswap(e[1], e[3], up);
                    cswap(e[4], e[6], up); cswap(e[5], e[7], up);
                    cswap(e[0], e[1], up); cswap(e[2], e[3], up);
                    cswap(e[4], e[5], up); cswap(e[6], e[7], up);
#pragma unroll
                    for (int t = 0; t < 8; ++t) sk[PHI(b + (t << ls))] = e[t];
                }
                j >>= 3;
            } else if (L == 2) {   // fuse strides j, j/2  (s = j/2)
                const int ls = lj - 1;
                const int sm = (1 << ls) - 1;
#pragma unroll
                for (int gg = 0; gg < SORT_N / 4 / SORT_T; ++gg) {
                    const int g = tid + gg * SORT_T;
                    const int b = ((g >> ls) << (ls + 2)) | (g & sm);
                    unsigned long long e[4];
#pragma unroll
                    for (int t = 0; t < 4; ++t) e[t] = sk[PHI(b + (t << ls))];
                    const bool up = ((b & k2) == 0);
                    cswap(e[0], e[2], up); cswap(e[1], e[3], up);
                    cswap(e[0], e[1], up); cswap(e[2], e[3], up);
#pragma unroll
                    for (int t = 0; t < 4; ++t) sk[PHI(b + (t << ls))] = e[t];
                }
                j >>= 2;
            } else {               // single pair pass at stride j
                const int ls = lj;
                const int sm = j - 1;
#pragma unroll
                for (int gg = 0; gg < SORT_N / 2 / SORT_T; ++gg) {
                    const int g = tid + gg * SORT_T;
                    const int b = ((g >> ls) << (ls + 1)) | (g & sm);
                    unsigned long long a = sk[PHI(b)];
                    unsigned long long c = sk[PHI(b + j)];
                    const bool up = ((b & k2) == 0);
                    cswap(a, c, up);
                    sk[PHI(b)] = a;
                    sk[PHI(b + j)] = c;
                }
                j >>= 1;
            }
        }
        __syncthreads();
        const bool up = ((base & k2) == 0);  // uniform per chunk (k2 >= 32)
#pragma unroll
        for (int q = 0; q < EPT; ++q) r[q] = sk[base | (q ^ sw)];
#pragma unroll
        for (int j2 = EPT / 2; j2 > 0; j2 >>= 1) {
#pragma unroll
            for (int q = 0; q < EPT; ++q) {
                const int l = q ^ j2;
                if (l > q) cswap(r[q], r[l], up);
            }
        }
        if (k2 < SORT_N) {
#pragma unroll
            for (int q = 0; q < EPT; ++q) sk[base | (q ^ sw)] = r[q];
        }
    }

    if (pb < NPROJ) {
        unsigned short* rk = rxOut + (size_t)pb * NPATCH;
#pragma unroll
        for (int q = 0; q < EPT; ++q) {
            const int idx = (int)(r[q] & 0x1FFFu);
            if (idx < NPATCH) rk[idx] = (unsigned short)(base + q);
        }
    } else {
        unsigned short* io = iyOut + (size_t)(pb - NPROJ) * NPATCH;
#pragma unroll
        for (int q = 0; q < EPT; ++q) {
            if (base + q < NPATCH) io[base + q] = (unsigned short)(r[q] & 0x1FFFu);
        }
    }
}

// ---------------------------------------------------------------------------
// Kernel B2: partner[p][i] = iy[p][ rx[p][i] ].
// ---------------------------------------------------------------------------
__global__ __launch_bounds__(256)
void partner_kernel(const unsigned short* __restrict__ rx,
                    const unsigned short* __restrict__ iy,
                    unsigned short* __restrict__ partner)
{
    const int p = blockIdx.x;
    const int ipb = (NPATCH + gridDim.y - 1) / gridDim.y;
    const int i0 = blockIdx.y * ipb;
    const int iend = min(i0 + ipb, NPATCH);
    const unsigned short* rxp = rx + (size_t)p * NPATCH;
    const unsigned short* iyp = iy + (size_t)p * NPATCH;
    unsigned short* pp = partner + (size_t)p * NPATCH;
    for (int i = i0 + threadIdx.x; i < iend; i += 256)
        pp[i] = iyp[rxp[i]];
}

// ---------------------------------------------------------------------------
// Kernel C: loss = mean over (p, i, d) of |xp[i, d] - yp[partner[p][i], d]|.
// Main pass: 4 rows per wave-iteration; x-load = one coalesced dwordx4 over 4
// consecutive rows, y-load = dwordx4 with 16-lane groups per random row.
// Partner index prefetched one iteration ahead. Packed-fp16 sub/abs/add.
// ---------------------------------------------------------------------------
__global__ __launch_bounds__(256)
void reduce_kernel(const __half* __restrict__ xmain, const __half* __restrict__ ymain,
                   const __half* __restrict__ xtail, const __half* __restrict__ ytail,
                   const unsigned short* __restrict__ partner,
                   float* __restrict__ out)
{
    const int p = blockIdx.x;
    const int i0 = blockIdx.y * KPB;
    const int iend = min(i0 + KPB, NPATCH);
    const int tid = threadIdx.x;
    const int wave = tid >> 6, lane = tid & 63;
    const unsigned short* par = partner + (size_t)p * NPATCH;

    __half2 a0 = __float2half2_rn(0.f), a1 = a0, a2 = a0, a3 = a0;

    // ---- main pass: d = 0..127 ----
    {
        const int g = lane >> 4;   // row within quad
        const int u = lane & 15;   // 16B unit within row
        int i = i0 + wave * 4;
        if (i < iend) {
            int j = par[i + g];
            for (; i < iend; i += 16) {
                const int pi = min(i + 16 + g, NPATCH - 1);  // prefetch (clamped)
                const int jn = par[pi];
                Pack16 xa, ya;
                xa.f = ((const float4*)xmain)[(size_t)i * 16 + lane];
                ya.f = ((const float4*)ymain)[(size_t)j * 16 + u];
                a0 = __hadd2(a0, __habs2(__hsub2(xa.h[0], ya.h[0])));
                a1 = __hadd2(a1, __habs2(__hsub2(xa.h[1], ya.h[1])));
                a2 = __hadd2(a2, __habs2(__hsub2(xa.h[2], ya.h[2])));
                a3 = __hadd2(a3, __habs2(__hsub2(xa.h[3], ya.h[3])));
                j = jn;
            }
        }
    }

    // ---- tail pass: d = 128..146 (+ zero pad to 160) ----
    {
        const int g2 = lane >> 2;  // row within 16-row group
        const int u2 = lane & 3;   // 16B unit within tail row
        for (int i2 = i0 + wave * 16; i2 < iend; i2 += 64) {
            const int r = i2 + g2;
            if (r < iend) {
                const int j = par[r];
                Pack16 xa, ya;
                xa.f = ((const float4*)xtail)[(size_t)i2 * 4 + lane];
                ya.f = ((const float4*)ytail)[(size_t)j * 4 + u2];
                a0 = __hadd2(a0, __habs2(__hsub2(xa.h[0], ya.h[0])));
                a1 = __hadd2(a1, __habs2(__hsub2(xa.h[1], ya.h[1])));
                a2 = __hadd2(a2, __habs2(__hsub2(xa.h[2], ya.h[2])));
                a3 = __hadd2(a3, __habs2(__hsub2(xa.h[3], ya.h[3])));
            }
        }
    }

    const float2 f0 = __half22float2(a0);
    const float2 f1 = __half22float2(a1);
    const float2 f2 = __half22float2(a2);
    const float2 f3 = __half22float2(a3);
    float acc = f0.x + f0.y + f1.x + f1.y + f2.x + f2.y + f3.x + f3.y;

#pragma unroll
    for (int o = 32; o > 0; o >>= 1) acc += __shfl_down(acc, o, 64);

    __shared__ float sred[4];
    if (lane == 0) sred[wave] = acc;
    __syncthreads();
    if (tid == 0) {
        const float s = sred[0] + sred[1] + sred[2] + sred[3];
        atomicAdd(out, s * (1.0f / ((float)NPROJ * (float)NPATCH * (float)DD)));
    }
}

// ---------------------------------------------------------------------------
extern "C" void kernel_launch(void* const* d_in, const int* in_sizes, int n_in,
                              void* d_out, int out_size, void* d_ws, size_t ws_size,
                              hipStream_t stream)
{
    const float* x   = (const float*)d_in[0];
    const float* y   = (const float*)d_in[1];
    const float* rnd = (const float*)d_in[2];

    char* ws = (char*)d_ws;
    // workspace layout (16B-aligned; pxT|pyT adjacent for sort; partner
    // aliases pxT — pxT is dead once sort_kernel has run):
    __half* xmain = (__half*)(ws + 0);          // 8100*128*2 = 2,073,600
    __half* ymain = (__half*)(ws + 2073600);    // 2,073,600
    __half* xtail = (__half*)(ws + 4147200);    // 8100*32*2  =   518,400
    __half* ytail = (__half*)(ws + 4665600);    //               518,400
    float*  pxT   = (float*)(ws + 5184000);     // 256*8100*4 = 8,294,400
    float*  pyT   = (float*)(ws + 13478400);    //             8,294,400
    unsigned short* rx      = (unsigned short*)(ws + 21772800);  // 4,147,200
    unsigned short* iy      = (unsigned short*)(ws + 25920000);  // 4,147,200
    unsigned short* partner = (unsigned short*)(ws + 5184000);   // alias pxT
    // high-water: 30,067,200 bytes
    float* out = (float*)d_out;

    hipLaunchKernelGGL(patch_proj_kernel, dim3((NPATCH + TN - 1) / TN, 2), dim3(256), 0, stream,
                       x, y, rnd, xmain, ymain, xtail, ytail, pxT, pyT, out);
    hipLaunchKernelGGL(sort_kernel, dim3(2 * NPROJ), dim3(SORT_T), 0, stream,
                       pxT, rx, iy);
    hipLaunchKernelGGL(partner_kernel, dim3(NPROJ, 4), dim3(256), 0, stream,
                       rx, iy, partner);
    hipLaunchKernelGGL(reduce_kernel, dim3(NPROJ, RCH), dim3(256), 0, stream,
                       xmain, ymain, xtail, ytail, partner, out);
}

// Round 7
// 202.747 us; speedup vs baseline: 3.8174x; 1.1759x over previous
//
#include <hip/hip_runtime.h>
#include <hip/hip_fp16.h>

#define HH 96
#define WW 96
#define OH 90
#define OW 90
#define NPATCH 8100
#define DD 147
#define DPAD 148
#define NPROJ 256
#define TN 32
#define SORT_N 8192
#define SORT_T 512
#define EPT 16
#define PGRP 32        // reduce: projections per block (x-register reuse factor)
#define NCH 64         // reduce: row chunks (grid.x)
#define KPB2 128       // reduce: rows per chunk (64*128 >= 8100; chunks stay %4)

// physical LDS slot for logical index i: XOR-swizzle low 4 bits with bits 4..7
#define PHI(i) ((i) ^ (((i) >> 4) & 15))

union Pack16 { float4 f; __half2 h[4]; };

__device__ __forceinline__ void cswap(unsigned long long& a, unsigned long long& b, bool up) {
    if ((a > b) == up) { unsigned long long t = a; a = b; b = t; }
}

// ---------------------------------------------------------------------------
// Kernel A: one image per block (blockIdx.y selects x/y). Stage 32x148 f32
// patch tile in LDS (Unfold layout f = c*49+di*7+dj), write fp16 split gather
// copies (main 128 + tail 32), then project: thread (q=tid&63, th=tid>>6)
// computes 8 patches x 4 projections; patch LDS reads are wave-broadcast,
// rnd reads are coalesced float4, epilogue stores are float4.
// std-normalization of rand is skipped: positive per-column scale cannot
// change the per-column argsort.
// ---------------------------------------------------------------------------
__global__ __launch_bounds__(256, 4)
void patch_proj_kernel(const float* __restrict__ x, const float* __restrict__ y,
                       const float* __restrict__ rnd,
                       __half* __restrict__ xmain, __half* __restrict__ ymain,
                       __half* __restrict__ xtail, __half* __restrict__ ytail,
                       float* __restrict__ pxT, float* __restrict__ pyT,
                       float* __restrict__ out)
{
    __shared__ float s[TN * DPAD];
    const int tid = threadIdx.x;
    const int n0 = blockIdx.x * TN;
    const int img = blockIdx.y;
    const float* __restrict__ src = img ? y : x;
    __half* __restrict__ mout = img ? ymain : xmain;
    __half* __restrict__ tout = img ? ytail : xtail;
    float* __restrict__ pT = img ? pyT : pxT;
    if (blockIdx.x == 0 && img == 0 && tid == 0) out[0] = 0.0f;

    for (int idx = tid; idx < TN * DPAD; idx += 256) {
        const int t = idx / DPAD;
        const int d = idx - t * DPAD;
        const int n = n0 + t;
        float v = 0.f;
        if (n < NPATCH && d < DD) {
            const int oy = n / OW, ox = n - oy * OW;
            const int c  = d / 49, r  = d - c * 49;
            const int di = r / 7,  dj = r - di * 7;
            v = src[c * (HH * WW) + (oy + di) * WW + (ox + dj)];
        }
        s[idx] = v;
    }
    __syncthreads();

    for (int idx = tid; idx < TN * 80; idx += 256) {
        const int t = idx / 80;
        const int u = idx - t * 80;
        const int n = n0 + t;
        if (n >= NPATCH) continue;
        if (u < 64) {
            const int d = 2 * u;
            ((__half2*)mout)[(size_t)n * 64 + u] =
                __floats2half2_rn(s[t * DPAD + d], s[t * DPAD + d + 1]);
        } else {
            const int ut = u - 64;
            const int d = 128 + 2 * ut;
            const float a0 = (d     < DPAD) ? s[t * DPAD + d]     : 0.f;
            const float a1 = (d + 1 < DPAD) ? s[t * DPAD + d + 1] : 0.f;
            ((__half2*)tout)[(size_t)n * 16 + ut] = __floats2half2_rn(a0, a1);
        }
    }

    const int q  = tid & 63;
    const int t0 = (tid >> 6) * 8;
    const float4* __restrict__ rnd4 = (const float4*)rnd;  // [147][64] float4s

    float acc[8][4];
#pragma unroll
    for (int t = 0; t < 8; ++t)
#pragma unroll
        for (int r = 0; r < 4; ++r) acc[t][r] = 0.f;

    for (int d = 0; d < 144; d += 4) {
        const float4 r0 = rnd4[(d + 0) * 64 + q];
        const float4 r1 = rnd4[(d + 1) * 64 + q];
        const float4 r2 = rnd4[(d + 2) * 64 + q];
        const float4 r3 = rnd4[(d + 3) * 64 + q];
#pragma unroll
        for (int t = 0; t < 8; ++t) {
            const float4 v = *(const float4*)&s[(t0 + t) * DPAD + d];
            acc[t][0] += v.x * r0.x + v.y * r1.x + v.z * r2.x + v.w * r3.x;
            acc[t][1] += v.x * r0.y + v.y * r1.y + v.z * r2.y + v.w * r3.y;
            acc[t][2] += v.x * r0.z + v.y * r1.z + v.z * r2.z + v.w * r3.z;
            acc[t][3] += v.x * r0.w + v.y * r1.w + v.z * r2.w + v.w * r3.w;
        }
    }
    {
        const float4 r0 = rnd4[144 * 64 + q];
        const float4 r1 = rnd4[145 * 64 + q];
        const float4 r2 = rnd4[146 * 64 + q];
#pragma unroll
        for (int t = 0; t < 8; ++t) {
            const float4 v = *(const float4*)&s[(t0 + t) * DPAD + 144];
            acc[t][0] += v.x * r0.x + v.y * r1.x + v.z * r2.x;
            acc[t][1] += v.x * r0.y + v.y * r1.y + v.z * r2.y;
            acc[t][2] += v.x * r0.z + v.y * r1.z + v.z * r2.z;
            acc[t][3] += v.x * r0.w + v.y * r1.w + v.z * r2.w;
        }
    }

    const int nb = n0 + t0;
#pragma unroll
    for (int r = 0; r < 4; ++r) {
        float* row = pT + (size_t)(4 * q + r) * NPATCH + nb;
        if (nb + 7 < NPATCH) {
            float4 lo, hi;
            lo.x = acc[0][r]; lo.y = acc[1][r]; lo.z = acc[2][r]; lo.w = acc[3][r];
            hi.x = acc[4][r]; hi.y = acc[5][r]; hi.z = acc[6][r]; hi.w = acc[7][r];
            ((float4*)row)[0] = lo;
            ((float4*)row)[1] = hi;
        } else {
#pragma unroll
            for (int t = 0; t < 8; ++t)
                if (nb + t < NPATCH) row[t] = acc[t][r];
        }
    }
}

// ---------------------------------------------------------------------------
// Kernel B: per-column argsort via hybrid register/LDS bitonic sort of 8192
// packed u64 keys (order-preserving f32 transform << 13 | index = stable).
// XOR-swizzled LDS layout (PHI); up to 3 bitonic levels fused per session.
// blockIdx.x in [0,512): cols of pxT (write RANK rx[idx]=k) then pyT
// (write iy[k]=idx).
// ---------------------------------------------------------------------------
__global__ __launch_bounds__(SORT_T, 4)
void sort_kernel(const float* __restrict__ pT,
                 unsigned short* __restrict__ rxOut,
                 unsigned short* __restrict__ iyOut)
{
    __shared__ unsigned long long sk[SORT_N];  // 64 KB
    const int pb = blockIdx.x;
    const int tid = threadIdx.x;
    const float* col = pT + (size_t)pb * NPATCH;

    for (int i = tid; i < SORT_N; i += SORT_T) {
        unsigned long long v;
        if (i < NPATCH) {
            const unsigned u = __float_as_uint(col[i]);
            const unsigned s = (u & 0x80000000u) ? ~u : (u | 0x80000000u);
            v = ((unsigned long long)s << 13) | (unsigned)i;
        } else {
            v = ~0ull;  // +inf pad, strictly greater than any finite key
        }
        sk[PHI(i)] = v;
    }
    __syncthreads();

    const int base = tid * EPT;
    const int sw = tid & 15;  // chunk-local swizzle: slot = base | (q ^ sw)
    unsigned long long r[EPT];

#pragma unroll
    for (int q = 0; q < EPT; ++q) r[q] = sk[base | (q ^ sw)];
#pragma unroll
    for (int k2 = 2; k2 <= EPT; k2 <<= 1) {
#pragma unroll
        for (int j = k2 >> 1; j > 0; j >>= 1) {
#pragma unroll
            for (int q = 0; q < EPT; ++q) {
                const int l = q ^ j;
                if (l > q) {
                    const bool up = (((base + q) & k2) == 0);
                    cswap(r[q], r[l], up);
                }
            }
        }
    }
#pragma unroll
    for (int q = 0; q < EPT; ++q) sk[base | (q ^ sw)] = r[q];

    for (int k2 = 32; k2 <= SORT_N; k2 <<= 1) {
        int j = k2 >> 1;
        while (j >= EPT) {
            __syncthreads();
            const int lj = 31 - __clz(j);
            const int L = lj - 3;
            if (L >= 3) {
                const int ls = lj - 2;
                const int sm = (1 << ls) - 1;
#pragma unroll
                for (int gg = 0; gg < SORT_N / 8 / SORT_T; ++gg) {
                    const int g = tid + gg * SORT_T;
                    const int b = ((g >> ls) << (ls + 3)) | (g & sm);
                    unsigned long long e[8];
#pragma unroll
                    for (int t = 0; t < 8; ++t) e[t] = sk[PHI(b + (t << ls))];
                    const bool up = ((b & k2) == 0);
                    cswap(e[0], e[4], up); cswap(e[1], e[5], up);
                    cswap(e[2], e[6], up); cswap(e[3], e[7], up);
                    cswap(e[0], e[2], up); cswap(e[1], e[3], up);
                    cswap(e[4], e[6], up); cswap(e[5], e[7], up);
                    cswap(e[0], e[1], up); cswap(e[2], e[3], up);
                    cswap(e[4], e[5], up); cswap(e[6], e[7], up);
#pragma unroll
                    for (int t = 0; t < 8; ++t) sk[PHI(b + (t << ls))] = e[t];
                }
                j >>= 3;
            } else if (L == 2) {
                const int ls = lj - 1;
                const int sm = (1 << ls) - 1;
#pragma unroll
                for (int gg = 0; gg < SORT_N / 4 / SORT_T; ++gg) {
                    const int g = tid + gg * SORT_T;
                    const int b = ((g >> ls) << (ls + 2)) | (g & sm);
                    unsigned long long e[4];
#pragma unroll
                    for (int t = 0; t < 4; ++t) e[t] = sk[PHI(b + (t << ls))];
                    const bool up = ((b & k2) == 0);
                    cswap(e[0], e[2], up); cswap(e[1], e[3], up);
                    cswap(e[0], e[1], up); cswap(e[2], e[3], up);
#pragma unroll
                    for (int t = 0; t < 4; ++t) sk[PHI(b + (t << ls))] = e[t];
                }
                j >>= 2;
            } else {
                const int ls = lj;
                const int sm = j - 1;
#pragma unroll
                for (int gg = 0; gg < SORT_N / 2 / SORT_T; ++gg) {
                    const int g = tid + gg * SORT_T;
                    const int b = ((g >> ls) << (ls + 1)) | (g & sm);
                    unsigned long long a = sk[PHI(b)];
                    unsigned long long c = sk[PHI(b + j)];
                    const bool up = ((b & k2) == 0);
                    cswap(a, c, up);
                    sk[PHI(b)] = a;
                    sk[PHI(b + j)] = c;
                }
                j >>= 1;
            }
        }
        __syncthreads();
        const bool up = ((base & k2) == 0);
#pragma unroll
        for (int q = 0; q < EPT; ++q) r[q] = sk[base | (q ^ sw)];
#pragma unroll
        for (int j2 = EPT / 2; j2 > 0; j2 >>= 1) {
#pragma unroll
            for (int q = 0; q < EPT; ++q) {
                const int l = q ^ j2;
                if (l > q) cswap(r[q], r[l], up);
            }
        }
        if (k2 < SORT_N) {
#pragma unroll
            for (int q = 0; q < EPT; ++q) sk[base | (q ^ sw)] = r[q];
        }
    }

    if (pb < NPROJ) {
        unsigned short* rk = rxOut + (size_t)pb * NPATCH;
#pragma unroll
        for (int q = 0; q < EPT; ++q) {
            const int idx = (int)(r[q] & 0x1FFFu);
            if (idx < NPATCH) rk[idx] = (unsigned short)(base + q);
        }
    } else {
        unsigned short* io = iyOut + (size_t)(pb - NPROJ) * NPATCH;
#pragma unroll
        for (int q = 0; q < EPT; ++q) {
            if (base + q < NPATCH) io[base + q] = (unsigned short)(r[q] & 0x1FFFu);
        }
    }
}

// ---------------------------------------------------------------------------
// Kernel B2: partner[p][i] = iy[p][ rx[p][i] ].
// ---------------------------------------------------------------------------
__global__ __launch_bounds__(256)
void partner_kernel(const unsigned short* __restrict__ rx,
                    const unsigned short* __restrict__ iy,
                    unsigned short* __restrict__ partner)
{
    const int p = blockIdx.x;
    const int ipb = (NPATCH + gridDim.y - 1) / gridDim.y;
    const int i0 = blockIdx.y * ipb;
    const int iend = min(i0 + ipb, NPATCH);
    const unsigned short* rxp = rx + (size_t)p * NPATCH;
    const unsigned short* iyp = iy + (size_t)p * NPATCH;
    unsigned short* pp = partner + (size_t)p * NPATCH;
    for (int i = i0 + threadIdx.x; i < iend; i += 256)
        pp[i] = iyp[rxp[i]];
}

// ---------------------------------------------------------------------------
// Kernel C (v3): loss = mean over (p, i, d) of |x[i,d] - y[partner[p][i],d]|.
// Block = (row chunk, group of 32 projections). Main pass: wave loads an
// x-quad (4 rows, dwordx4) ONCE into registers, then loops the 32 projections
// gathering only y — x traffic drops 32x (was half the kernel's 1.33 GB).
// fp16 accumulators spilled to fp32 every i-iteration (<=32 adds per slot).
// ---------------------------------------------------------------------------
__global__ __launch_bounds__(256)
void reduce_kernel(const __half* __restrict__ xmain, const __half* __restrict__ ymain,
                   const __half* __restrict__ xtail, const __half* __restrict__ ytail,
                   const unsigned short* __restrict__ partner,
                   float* __restrict__ out)
{
    const int p0 = blockIdx.y * PGRP;
    const int i0 = blockIdx.x * KPB2;
    const int iend = min(i0 + KPB2, NPATCH);
    const int tid = threadIdx.x;
    const int wave = tid >> 6, lane = tid & 63;

    float facc = 0.f;

    // ---- main pass: d = 0..127, 4 rows per wave-iter ----
    {
        const int g = lane >> 4;   // row within quad
        const int u = lane & 15;   // 16B unit within row
        for (int i = i0 + wave * 4; i < iend; i += 16) {
            Pack16 xa;
            xa.f = ((const float4*)xmain)[(size_t)i * 16 + lane];
            __half2 a0 = __float2half2_rn(0.f), a1 = a0, a2 = a0, a3 = a0;
#pragma unroll 8
            for (int pp = 0; pp < PGRP; ++pp) {
                const int j = partner[(size_t)(p0 + pp) * NPATCH + i + g];
                Pack16 ya;
                ya.f = ((const float4*)ymain)[(size_t)j * 16 + u];
                a0 = __hadd2(a0, __habs2(__hsub2(xa.h[0], ya.h[0])));
                a1 = __hadd2(a1, __habs2(__hsub2(xa.h[1], ya.h[1])));
                a2 = __hadd2(a2, __habs2(__hsub2(xa.h[2], ya.h[2])));
                a3 = __hadd2(a3, __habs2(__hsub2(xa.h[3], ya.h[3])));
            }
            const float2 f0 = __half22float2(a0);
            const float2 f1 = __half22float2(a1);
            const float2 f2 = __half22float2(a2);
            const float2 f3 = __half22float2(a3);
            facc += (f0.x + f0.y) + (f1.x + f1.y) + (f2.x + f2.y) + (f3.x + f3.y);
        }
    }

    // ---- tail pass: d = 128..146 (+ zero pad), 16 rows per wave-iter ----
    {
        const int g2 = lane >> 2;  // row within 16-row group
        const int u2 = lane & 3;   // 16B unit within tail row
        for (int i2 = i0 + wave * 16; i2 < iend; i2 += 64) {
            const int r = i2 + g2;
            if (r < iend) {
                Pack16 xa;
                xa.f = ((const float4*)xtail)[(size_t)i2 * 4 + lane];
                __half2 a0 = __float2half2_rn(0.f), a1 = a0, a2 = a0, a3 = a0;
#pragma unroll 8
                for (int pp = 0; pp < PGRP; ++pp) {
                    const int j = partner[(size_t)(p0 + pp) * NPATCH + r];
                    Pack16 ya;
                    ya.f = ((const float4*)ytail)[(size_t)j * 4 + u2];
                    a0 = __hadd2(a0, __habs2(__hsub2(xa.h[0], ya.h[0])));
                    a1 = __hadd2(a1, __habs2(__hsub2(xa.h[1], ya.h[1])));
                    a2 = __hadd2(a2, __habs2(__hsub2(xa.h[2], ya.h[2])));
                    a3 = __hadd2(a3, __habs2(__hsub2(xa.h[3], ya.h[3])));
                }
                const float2 f0 = __half22float2(a0);
                const float2 f1 = __half22float2(a1);
                const float2 f2 = __half22float2(a2);
                const float2 f3 = __half22float2(a3);
                facc += (f0.x + f0.y) + (f1.x + f1.y) + (f2.x + f2.y) + (f3.x + f3.y);
            }
        }
    }

#pragma unroll
    for (int o = 32; o > 0; o >>= 1) facc += __shfl_down(facc, o, 64);

    __shared__ float sred[4];
    if (lane == 0) sred[wave] = facc;
    __syncthreads();
    if (tid == 0) {
        const float s = sred[0] + sred[1] + sred[2] + sred[3];
        atomicAdd(out, s * (1.0f / ((float)NPROJ * (float)NPATCH * (float)DD)));
    }
}

// ---------------------------------------------------------------------------
extern "C" void kernel_launch(void* const* d_in, const int* in_sizes, int n_in,
                              void* d_out, int out_size, void* d_ws, size_t ws_size,
                              hipStream_t stream)
{
    const float* x   = (const float*)d_in[0];
    const float* y   = (const float*)d_in[1];
    const float* rnd = (const float*)d_in[2];

    char* ws = (char*)d_ws;
    // workspace layout (16B-aligned; pxT|pyT adjacent for sort; partner
    // aliases pxT — pxT is dead once sort_kernel has run):
    __half* xmain = (__half*)(ws + 0);          // 8100*128*2 = 2,073,600
    __half* ymain = (__half*)(ws + 2073600);    // 2,073,600
    __half* xtail = (__half*)(ws + 4147200);    // 8100*32*2  =   518,400
    __half* ytail = (__half*)(ws + 4665600);    //               518,400
    float*  pxT   = (float*)(ws + 5184000);     // 256*8100*4 = 8,294,400
    float*  pyT   = (float*)(ws + 13478400);    //             8,294,400
    unsigned short* rx      = (unsigned short*)(ws + 21772800);  // 4,147,200
    unsigned short* iy      = (unsigned short*)(ws + 25920000);  // 4,147,200
    unsigned short* partner = (unsigned short*)(ws + 5184000);   // alias pxT
    // high-water: 30,067,200 bytes
    float* out = (float*)d_out;

    hipLaunchKernelGGL(patch_proj_kernel, dim3((NPATCH + TN - 1) / TN, 2), dim3(256), 0, stream,
                       x, y, rnd, xmain, ymain, xtail, ytail, pxT, pyT, out);
    hipLaunchKernelGGL(sort_kernel, dim3(2 * NPROJ), dim3(SORT_T), 0, stream,
                       pxT, rx, iy);
    hipLaunchKernelGGL(partner_kernel, dim3(NPROJ, 4), dim3(256), 0, stream,
                       rx, iy, partner);
    hipLaunchKernelGGL(reduce_kernel, dim3(NCH, NPROJ / PGRP), dim3(256), 0, stream,
                       xmain, ymain, xtail, ytail, partner, out);
}